// Round 12
// baseline (324.026 us; speedup 1.0000x reference)
//
#include <hip/hip_runtime.h>
#include <cstdint>

#define NB 32
#define NNODES 1024
#define DD 256
#define KNB 64
#define MTOT (NB * NNODES)  // 32768

// Scaling: activations stored as split(64*a), weights as split(1024*w).
// acc = sum (64a)(1024w) = 65536 * a.w  -> epilogue * 1/65536.
// scores acc = (64q).(64k) = 4096 q.k -> q.k/16 = acc/65536 too.
#define INV65536 1.52587890625e-05f
// 16-bit key cell over [-8,8)
#define KCELL 2.44140625e-4f

typedef _Float16 half8 __attribute__((ext_vector_type(8)));
typedef _Float16 half4 __attribute__((ext_vector_type(4)));
typedef float f32x4 __attribute__((ext_vector_type(4)));

typedef __attribute__((address_space(3))) uint32_t lds_u32;
typedef __attribute__((address_space(1))) uint32_t glb_u32;

// 16B async global->LDS. LDS dest wave-uniform; HW adds lane*16.
__device__ __forceinline__ void gll16(const _Float16* g, _Float16* l) {
  __builtin_amdgcn_global_load_lds((const glb_u32*)g, (lds_u32*)l, 16, 0, 0);
}

__device__ __forceinline__ void split2(float v, _Float16& h, _Float16& l) {
  h = (_Float16)v;
  l = (_Float16)(v - (float)h);
}

// =====================================================================
// prep_w: W[k][n] fp32 -> W_T[n][k] fp16x2, scaled by 1024.
// =====================================================================
__global__ __launch_bounds__(256) void prep_w(const float* __restrict__ wq,
                                              const float* __restrict__ wk,
                                              const float* __restrict__ wv,
                                              const float* __restrict__ w1,
                                              const float* __restrict__ w2,
                                              _Float16* __restrict__ WT) {
  const int idx = blockIdx.x * 256 + threadIdx.x;  // < 5*65536
  const int wsel = idx >> 16;
  const int rem = idx & 65535;
  const int k = rem >> 8, n = rem & 255;
  const float* src = (wsel == 0) ? wq : (wsel == 1) ? wk : (wsel == 2) ? wv : (wsel == 3) ? w1 : w2;
  const float v = src[rem] * 1024.0f;
  _Float16 h1, h2;
  split2(v, h1, h2);
  WT[(size_t)wsel * 131072 + n * 256 + k] = h1;
  WT[(size_t)wsel * 131072 + 65536 + n * 256 + k] = h2;
}

// =====================================================================
// prep_x: x fp32 -> X1,X2 = split(64*x) fp16. 8 elems/thread, coalesced.
// =====================================================================
__global__ __launch_bounds__(256) void prep_x(const float* __restrict__ x,
                                              _Float16* __restrict__ X1,
                                              _Float16* __restrict__ X2) {
  const size_t i = ((size_t)blockIdx.x * 256 + threadIdx.x) * 8;
  const float4 a = *(const float4*)(x + i);
  const float4 bb = *(const float4*)(x + i + 4);
  const float vals[8] = {a.x, a.y, a.z, a.w, bb.x, bb.y, bb.z, bb.w};
  half8 h, l;
#pragma unroll
  for (int e = 0; e < 8; ++e) {
    _Float16 hh, ll;
    split2(vals[e] * 64.0f, hh, ll);
    h[e] = hh;
    l[e] = ll;
  }
  *(half8*)(X1 + i) = h;
  *(half8*)(X2 + i) = l;
}

// LDS tile layout: [128 rows][8 chunks of 8 halfs], chunk XOR-swizzled by (row&7)
#define SWZ_OFF(r, cc) ((r) * 64 + (((cc) ^ ((r)&7)) << 3))

// =====================================================================
// gemm_qkv: A=X1/X2 pre-split, B=WT, all via global_load_lds.
// Q,K: 3 products (selection-critical). V: 1 product -> fp16 only.
// Grid 1D 1536, XCD-swizzled: 6 sibling blocks (same m-rows) per XCD.
// =====================================================================
__global__ __launch_bounds__(256) void gemm_qkv(const _Float16* __restrict__ X1,
                                                const _Float16* __restrict__ X2,
                                                const _Float16* __restrict__ WT,
                                                const float* __restrict__ bq,
                                                const float* __restrict__ bk,
                                                const float* __restrict__ bv,
                                                _Float16* __restrict__ Q1, _Float16* __restrict__ Q2,
                                                _Float16* __restrict__ K1, _Float16* __restrict__ K2,
                                                _Float16* __restrict__ V16) {
  __shared__ _Float16 sm[4 * 8192];
  _Float16* sA1 = sm;
  _Float16* sA2 = sm + 8192;
  _Float16* sB1 = sm + 16384;
  _Float16* sB2 = sm + 24576;

  const int tid = threadIdx.x;
  const int lane = tid & 63, w = tid >> 6;
  const int r16 = lane & 15, kg = lane >> 4;
  const int rsub = lane >> 3, csub = lane & 7;
  const int wm = (w >> 1) * 64, wn = (w & 1) * 64;

  // XCD swizzle: id%8 = XCD; 6 siblings (j=0..5) of each m-tile share id%8
  const int id = blockIdx.x;
  const int c8 = id & 7, t = id >> 3;   // t in 0..191
  const int gy = (t / 6) * 8 + c8;      // m-tile 0..255
  const int j6 = t % 6;
  const int wsel = j6 >> 1;
  const int n0 = (j6 & 1) * 128;
  const int m0 = gy * 128;
  const bool full = (wsel != 2);  // Q,K need 3 products; V needs 1

  const _Float16* pB1 = WT + (size_t)wsel * 131072;
  const _Float16* pB2 = pB1 + 65536;

  f32x4 acc[4][4];
#pragma unroll
  for (int i = 0; i < 4; ++i)
#pragma unroll
    for (int j = 0; j < 4; ++j) acc[i][j] = f32x4{0.f, 0.f, 0.f, 0.f};

  for (int k0 = 0; k0 < DD; k0 += 64) {
    __syncthreads();
#pragma unroll
    for (int it = 0; it < 4; ++it) {
      const int r = (w << 5) + (it << 3) + rsub;
      const int swz = ((csub ^ (r & 7)) << 3);
      const int ldso = (w << 11) + (it << 9);
      gll16(X1 + (size_t)(m0 + r) * DD + k0 + swz, sA1 + ldso);
      gll16(pB1 + (size_t)(n0 + r) * DD + k0 + swz, sB1 + ldso);
      if (full) {
        gll16(X2 + (size_t)(m0 + r) * DD + k0 + swz, sA2 + ldso);
        gll16(pB2 + (size_t)(n0 + r) * DD + k0 + swz, sB2 + ldso);
      }
    }
    __syncthreads();

#pragma unroll
    for (int s = 0; s < 2; ++s) {
      half8 aA[4], aB[4], bA[4], bB[4];
#pragma unroll
      for (int mi = 0; mi < 4; ++mi) {
        const int off = SWZ_OFF(wm + mi * 16 + r16, s * 4 + kg);
        aA[mi] = *(const half8*)(sA1 + off);
      }
#pragma unroll
      for (int nj = 0; nj < 4; ++nj) {
        const int off = SWZ_OFF(wn + nj * 16 + r16, s * 4 + kg);
        bA[nj] = *(const half8*)(sB1 + off);
      }
      if (full) {
#pragma unroll
        for (int mi = 0; mi < 4; ++mi) {
          const int off = SWZ_OFF(wm + mi * 16 + r16, s * 4 + kg);
          aB[mi] = *(const half8*)(sA2 + off);
        }
#pragma unroll
        for (int nj = 0; nj < 4; ++nj) {
          const int off = SWZ_OFF(wn + nj * 16 + r16, s * 4 + kg);
          bB[nj] = *(const half8*)(sB2 + off);
        }
      }
#pragma unroll
      for (int mi = 0; mi < 4; ++mi)
#pragma unroll
        for (int nj = 0; nj < 4; ++nj) {
          acc[mi][nj] = __builtin_amdgcn_mfma_f32_16x16x32_f16(aA[mi], bA[nj], acc[mi][nj], 0, 0, 0);
          if (full) {
            acc[mi][nj] = __builtin_amdgcn_mfma_f32_16x16x32_f16(aA[mi], bB[nj], acc[mi][nj], 0, 0, 0);
            acc[mi][nj] = __builtin_amdgcn_mfma_f32_16x16x32_f16(aB[mi], bA[nj], acc[mi][nj], 0, 0, 0);
          }
        }
    }
  }

  const float* bsel = (wsel == 0) ? bq : (wsel == 1) ? bk : bv;
  _Float16* P1 = (wsel == 0) ? Q1 : K1;
  _Float16* P2 = (wsel == 0) ? Q2 : K2;
#pragma unroll
  for (int mi = 0; mi < 4; ++mi)
#pragma unroll
    for (int nj = 0; nj < 4; ++nj) {
      const int col = n0 + wn + nj * 16 + r16;
#pragma unroll
      for (int j = 0; j < 4; ++j) {
        const int rr = m0 + wm + mi * 16 + kg * 4 + j;
        if (wsel == 2) {
          V16[(size_t)rr * DD + col] = (_Float16)(acc[mi][nj][j] * INV65536 + bsel[col]);
        } else {
          // store 64*Q = acc/1024 + 64*bias
          const float qv = acc[mi][nj][j] * (1.0f / 1024.0f) + 64.0f * bsel[col];
          _Float16 h1, h2;
          split2(qv, h1, h2);
          P1[(size_t)rr * DD + col] = h1;
          P2[(size_t)rr * DD + col] = h2;
        }
      }
    }
}

// =====================================================================
// gemm_split<EPI>: A single-split fp16, B pre-split fp16x2 (NT).
// EPI 0: H16 = fp16(acc/65536 + bias)      (w1 -> H16), 2 products
// EPI 1: C = acc/65536 + bias + resid16    (w2 -> out), 2 products
// EPI 2: scores -> u16 keys (bytes 2048..4095 of each attn row's 4KB),
//        2 products; grid 1D 2048 XCD-swizzled (batch -> one XCD so
//        K_b stays L2-resident; keeps r7's proven direct u16 epilogue).
// =====================================================================
template <int EPI>
__global__ __launch_bounds__(256) void gemm_split(const _Float16* __restrict__ A1,
                                                  const _Float16* __restrict__ B1g,
                                                  const _Float16* __restrict__ B2g,
                                                  const float* __restrict__ bias,
                                                  const _Float16* __restrict__ resid16,
                                                  float* __restrict__ C,
                                                  _Float16* __restrict__ C16) {
  __shared__ _Float16 sm[3 * 8192];
  _Float16* sA1 = sm;
  _Float16* sB1 = sm + 8192;
  _Float16* sB2 = sm + 16384;

  const int tid = threadIdx.x;
  const int lane = tid & 63, w = tid >> 6;
  const int r16 = lane & 15, kg = lane >> 4;
  const int rsub = lane >> 3, csub = lane & 7;
  const int wm = (w >> 1) * 64, wn = (w & 1) * 64;

  int n0, m0;
  if (EPI == 2) {
    // XCD swizzle: batch Bb's 64 blocks share id%8 = one XCD
    const int id = blockIdx.x;
    const int c8 = id & 7, t = id >> 3;   // t in 0..255
    const int Bb = ((t >> 6) << 3) + c8;  // batch 0..31
    const int r = (t >> 3) & 7;           // m sub-tile
    const int bx = t & 7;                 // n tile
    n0 = bx * 128;
    m0 = (Bb * 8 + r) * 128;
  } else {
    n0 = blockIdx.x * 128;
    m0 = blockIdx.y * 128;
  }

  const _Float16* pB1 = B1g;
  const _Float16* pB2 = B2g;
  if (EPI == 2) {
    const size_t boff = (size_t)(m0 >> 10) * NNODES * DD;
    pB1 += boff;
    pB2 += boff;
  }

  f32x4 acc[4][4];
#pragma unroll
  for (int i = 0; i < 4; ++i)
#pragma unroll
    for (int j = 0; j < 4; ++j) acc[i][j] = f32x4{0.f, 0.f, 0.f, 0.f};

  for (int k0 = 0; k0 < DD; k0 += 64) {
    __syncthreads();
#pragma unroll
    for (int it = 0; it < 4; ++it) {
      const int r = (w << 5) + (it << 3) + rsub;
      const int swz = ((csub ^ (r & 7)) << 3);
      const int ldso = (w << 11) + (it << 9);
      gll16(A1 + (size_t)(m0 + r) * DD + k0 + swz, sA1 + ldso);
      gll16(pB1 + (size_t)(n0 + r) * DD + k0 + swz, sB1 + ldso);
      gll16(pB2 + (size_t)(n0 + r) * DD + k0 + swz, sB2 + ldso);
    }
    __syncthreads();

#pragma unroll
    for (int s = 0; s < 2; ++s) {
      half8 aA[4], bA[4], bB[4];
#pragma unroll
      for (int mi = 0; mi < 4; ++mi) {
        const int off = SWZ_OFF(wm + mi * 16 + r16, s * 4 + kg);
        aA[mi] = *(const half8*)(sA1 + off);
      }
#pragma unroll
      for (int nj = 0; nj < 4; ++nj) {
        const int off = SWZ_OFF(wn + nj * 16 + r16, s * 4 + kg);
        bA[nj] = *(const half8*)(sB1 + off);
        bB[nj] = *(const half8*)(sB2 + off);
      }
#pragma unroll
      for (int mi = 0; mi < 4; ++mi)
#pragma unroll
        for (int nj = 0; nj < 4; ++nj) {
          acc[mi][nj] = __builtin_amdgcn_mfma_f32_16x16x32_f16(aA[mi], bA[nj], acc[mi][nj], 0, 0, 0);
          acc[mi][nj] = __builtin_amdgcn_mfma_f32_16x16x32_f16(aA[mi], bB[nj], acc[mi][nj], 0, 0, 0);
        }
    }
  }

#pragma unroll
  for (int mi = 0; mi < 4; ++mi)
#pragma unroll
    for (int nj = 0; nj < 4; ++nj) {
      const int col = n0 + wn + nj * 16 + r16;
#pragma unroll
      for (int j = 0; j < 4; ++j) {
        const int rr = m0 + wm + mi * 16 + kg * 4 + j;
        const float v = acc[mi][nj][j] * INV65536;
        if (EPI == 2) {
          const float sv = v + bias[(size_t)(rr & (NNODES - 1)) * NNODES + col];
          const float f = fminf(fmaxf((sv + 8.0f) * 4096.0f, 0.0f), 65535.0f);
          uint16_t* kbase = (uint16_t*)((char*)C + (size_t)rr * 4096 + 2048);
          kbase[col] = (uint16_t)(unsigned)f;
        } else if (EPI == 0) {
          C16[(size_t)rr * DD + col] = (_Float16)(v + bias[col]);
        } else {
          C[(size_t)rr * DD + col] = v + bias[col] + (float)resid16[(size_t)rr * DD + col];
        }
      }
    }
}

// =====================================================================
// Top-64 from u16 keys + masked softmax + sparse messages. One wave/row.
// waves_per_eu(4,4): pin occupancy target so regalloc gets a 128-VGPR
// budget (r9/r10's 32-VGPR squeeze forced pervasive recompute -> 3x VALU).
// Fast path carries only k[16]+masks; position tracking (cpos/cidxs)
// lives exclusively in the rare slow path. Softmax from integer keys.
// Band: hi key>=cur+5 (provably in), out key<cur-4 (provably out);
// candidates: exact fp32 recompute, jax tie semantics.
// =====================================================================
__global__ __launch_bounds__(256) __attribute__((amdgpu_waves_per_eu(4, 4)))
void topk_softmax_msg(float* __restrict__ S,
                      const _Float16* __restrict__ V16,
                      const _Float16* __restrict__ Q1,
                      const _Float16* __restrict__ Q2,
                      const _Float16* __restrict__ K1,
                      const _Float16* __restrict__ K2,
                      const float* __restrict__ adj,
                      _Float16* __restrict__ M1) {
  const int tid = threadIdx.x;
  const int w = tid >> 6, lane = tid & 63;
  // XCD swizzle: batch = (t>>8)*8 + id%8 -> whole batch on one XCD
  const int id = blockIdx.x;            // 0..8191
  const int xcd = id & 7, t = id >> 3;  // t 0..1023
  const int b = (t >> 8) * 8 + xcd;     // batch 0..31
  const int row = b * NNODES + (t & 255) * 4 + w;
  const int m = row & (NNODES - 1);
  float* Srow = S + (size_t)row * NNODES;
  const uint16_t* krow = (const uint16_t*)((const char*)S + (size_t)row * 4096 + 2048);

  __shared__ float2 spair[4][KNB];  // (wgt, V16 row byte-offset bits)
  __shared__ int cidxs[4][32];
  __shared__ float cex[4][32];
  __shared__ int csel[4][32];

  if (lane < KNB) spair[w][lane] = make_float2(0.0f, __int_as_float(0));

  // load 16 keys: k[t] maps to col(t) = (t>>3)*512 + lane*8 + (t&7)
  const uint4 u0 = *(const uint4*)(krow + lane * 8);
  const uint4 u1 = *(const uint4*)(krow + 512 + lane * 8);
  int k[16];
  {
    const unsigned uu[8] = {u0.x, u0.y, u0.z, u0.w, u1.x, u1.y, u1.z, u1.w};
#pragma unroll
    for (int q = 0; q < 8; ++q) {
      k[q * 2] = (int)(uu[q] & 0xffffu);
      k[q * 2 + 1] = (int)(uu[q] >> 16);
    }
  }

  // radix-select 64th-largest key (16 bits)
  int cur = 0;
#pragma unroll 1
  for (int bit = 15; bit >= 0; --bit) {
    const int cand = cur | (1 << bit);
    int cnt = 0;
#pragma unroll
    for (int t2 = 0; t2 < 16; ++t2) cnt += (int)__popcll(__ballot(k[t2] >= cand));
    if (cnt >= KNB) cur = cand;
  }

  const int kHi = cur + 5;  // key >= kHi -> provably in top-64
  const int kLo = cur - 4;  // key <  kLo -> provably out

  // wave-wide integer key max (softmax base; max elem is always selected)
  int kx = k[0];
#pragma unroll
  for (int t2 = 1; t2 < 16; ++t2) kx = (k[t2] > kx) ? k[t2] : kx;
#pragma unroll
  for (int off = 32; off > 0; off >>= 1) {
    const int o = __shfl_xor(kx, off);
    kx = (o > kx) ? o : kx;
  }

  // classification: masks + counts only (no position tracking)
  unsigned hm = 0u, cm = 0u;
  int nhi = 0, ncand = 0;
#pragma unroll
  for (int t2 = 0; t2 < 16; ++t2) {
    const bool hiv = (k[t2] >= kHi);
    const bool cdv = (!hiv) && (k[t2] >= kLo);
    if (hiv) hm |= (1u << t2);
    if (cdv) cm |= (1u << t2);
    nhi += (int)__popcll(__ballot(hiv));
    ncand += (int)__popcll(__ballot(cdv));
  }
  const int need = KNB - nhi;  // >= 1; nhi+ncand >= 64

  unsigned selm;
  if (ncand == need) {
    selm = hm | cm;  // fast path (vast majority of rows)
  } else {
    // slow path: compact candidates in index order, exact fp32 recompute
    const unsigned long long ltm = (1ull << lane) - 1ull;
    int cpos[16];
    int nc0 = 0;
#pragma unroll
    for (int g = 0; g < 2; ++g) {
      bool cdv8[8];
      unsigned long long mcv[8];
#pragma unroll
      for (int e = 0; e < 8; ++e) {
        cdv8[e] = (cm >> (g * 8 + e)) & 1u;
        mcv[e] = __ballot(cdv8[e]);
      }
      int below = 0, tot = 0;
#pragma unroll
      for (int e = 0; e < 8; ++e) {
        below += (int)__popcll(mcv[e] & ltm);
        tot += (int)__popcll(mcv[e]);
      }
      int own = 0;
#pragma unroll
      for (int e = 0; e < 8; ++e) {
        const int t2 = g * 8 + e;
        cpos[t2] = -1;
        if (cdv8[e]) {
          const int p2 = nc0 + below + own;
          cpos[t2] = p2;
          if (p2 < 32) cidxs[w][p2] = g * 512 + lane * 8 + e;
          ++own;
        }
      }
      nc0 += tot;
    }
    const int nc = (ncand <= 32) ? ncand : 32;
    const int nd = (need <= nc) ? need : nc;
    const size_t qoff = (size_t)row * DD + lane * 4;
    const half4 q1v = *(const half4*)(Q1 + qoff);
    const half4 q2v = *(const half4*)(Q2 + qoff);
    float qf[4];
#pragma unroll
    for (int e = 0; e < 4; ++e) qf[e] = (float)q1v[e] + (float)q2v[e];
    const float* adjrow = adj + (size_t)m * NNODES;
#pragma unroll 2
    for (int t2 = 0; t2 < nc; ++t2) {
      const int j = cidxs[w][t2];
      const size_t koff = ((size_t)b * NNODES + j) * DD + lane * 4;
      const half4 k1v = *(const half4*)(K1 + koff);
      const half4 k2v = *(const half4*)(K2 + koff);
      float part = 0.0f;
#pragma unroll
      for (int e = 0; e < 4; ++e) part = fmaf(qf[e], (float)k1v[e] + (float)k2v[e], part);
#pragma unroll
      for (int off = 32; off > 0; off >>= 1) part += __shfl_xor(part, off);
      if (lane == 0) cex[w][t2] = part * INV65536 + adjrow[j];
    }
    if (lane < nc) {
      const float et = cex[w][lane];
      int rank = 0;
      for (int u = 0; u < nc; ++u) {
        const float eu = cex[w][u];
        rank += (eu > et || (eu == et && u < lane)) ? 1 : 0;
      }
      csel[w][lane] = (rank < nd) ? 1 : 0;
    }
    selm = hm;
#pragma unroll
    for (int t2 = 0; t2 < 16; ++t2) {
      if (((cm >> t2) & 1u) && cpos[t2] >= 0 && cpos[t2] < 32 && csel[w][cpos[t2]]) selm |= (1u << t2);
    }
  }

  // softmax over selected, directly from integer keys
  float p[16];
  float sum = 0.0f;
#pragma unroll
  for (int t2 = 0; t2 < 16; ++t2) {
    p[t2] = __expf((float)(k[t2] - kx) * KCELL);
    if ((selm >> t2) & 1u) sum += p[t2];
  }
#pragma unroll
  for (int off = 32; off > 0; off >>= 1) sum += __shfl_xor(sum, off);
  const float inv = 1.0f / sum;

  // attn write (overwrites full 4KB row incl. key half) + ordered compaction
  const unsigned long long ltmask = (1ull << lane) - 1ull;
  int run = 0;
#pragma unroll
  for (int g = 0; g < 2; ++g) {
    bool sel8[8];
    unsigned long long ms[8];
#pragma unroll
    for (int e = 0; e < 8; ++e) {
      sel8[e] = (selm >> (g * 8 + e)) & 1u;
      ms[e] = __ballot(sel8[e]);
    }
    int below = 0, tot = 0;
#pragma unroll
    for (int e = 0; e < 8; ++e) {
      below += (int)__popcll(ms[e] & ltmask);
      tot += (int)__popcll(ms[e]);
    }
    float ow[8];
    int own = 0;
#pragma unroll
    for (int e = 0; e < 8; ++e) {
      const int t2 = g * 8 + e;
      const float aw = sel8[e] ? p[t2] * inv : 0.0f;
      ow[e] = aw;
      if (sel8[e]) {
        const int pos = run + below + own;
        // store V16 row byte-offset: col * DD * 2
        if (pos < KNB)
          spair[w][pos] = make_float2(aw, __int_as_float((g * 512 + lane * 8 + e) * (DD * 2)));
        ++own;
      }
    }
    float* dst = Srow + g * 512 + lane * 8;
    *(float4*)(dst) = make_float4(ow[0], ow[1], ow[2], ow[3]);
    *(float4*)(dst + 4) = make_float4(ow[4], ow[5], ow[6], ow[7]);
    run += tot;
  }

  // messages: lane owns output dims [lane*4, lane*4+4)
  float4 acc = {0.0f, 0.0f, 0.0f, 0.0f};
  const char* Vbase = (const char*)(V16 + (size_t)b * NNODES * DD) + lane * 8;
#pragma unroll 4
  for (int t2 = 0; t2 < KNB; ++t2) {
    const float2 pr = spair[w][t2];
    const int off = __float_as_int(pr.y);
    const half4 vv = *(const half4*)(Vbase + off);
    acc.x = fmaf(pr.x, (float)vv[0], acc.x);
    acc.y = fmaf(pr.x, (float)vv[1], acc.y);
    acc.z = fmaf(pr.x, (float)vv[2], acc.z);
    acc.w = fmaf(pr.x, (float)vv[3], acc.w);
  }
  // M stored as single fp16(64*m) -- downstream w1 runs 2-product
  half4 m1;
  m1[0] = (_Float16)(acc.x * 64.0f);
  m1[1] = (_Float16)(acc.y * 64.0f);
  m1[2] = (_Float16)(acc.z * 64.0f);
  m1[3] = (_Float16)(acc.w * 64.0f);
  *(half4*)(M1 + (size_t)row * DD + lane * 4) = m1;
}

// =====================================================================
// LayerNorm + ReLU: H16 fp16 -> single fp16(64*y). Wave per row, no LDS.
// =====================================================================
__global__ __launch_bounds__(256) void ln_relu(const _Float16* __restrict__ H16,
                                               const float* __restrict__ g,
                                               const float* __restrict__ bta,
                                               _Float16* __restrict__ H1) {
  const int tid = threadIdx.x;
  const int row = blockIdx.x * 4 + (tid >> 6);
  const int lane = tid & 63;
  const half4 hv = *(const half4*)(H16 + (size_t)row * DD + lane * 4);
  float h[4];
#pragma unroll
  for (int j = 0; j < 4; ++j) h[j] = (float)hv[j];

  float s = h[0] + h[1] + h[2] + h[3];
#pragma unroll
  for (int off = 32; off > 0; off >>= 1) s += __shfl_xor(s, off);
  const float mu = s * (1.0f / 256.0f);

  float d[4], sq = 0.0f;
#pragma unroll
  for (int j = 0; j < 4; ++j) {
    d[j] = h[j] - mu;
    sq += d[j] * d[j];
  }
#pragma unroll
  for (int off = 32; off > 0; off >>= 1) sq += __shfl_xor(sq, off);
  const float rstd = 1.0f / sqrtf(sq * (1.0f / 256.0f) + 1e-5f);

  const float4 gv = *(const float4*)(g + lane * 4);
  const float4 bv = *(const float4*)(bta + lane * 4);
  const float gg[4] = {gv.x, gv.y, gv.z, gv.w};
  const float bb[4] = {bv.x, bv.y, bv.z, bv.w};
  half4 o;
#pragma unroll
  for (int j = 0; j < 4; ++j) {
    const float y = fmaxf(d[j] * rstd * gg[j] + bb[j], 0.0f);
    o[j] = (_Float16)(y * 64.0f);
  }
  *(half4*)(H1 + (size_t)row * DD + lane * 4) = o;
}

// =====================================================================
// Host launch
// =====================================================================
extern "C" void kernel_launch(void* const* d_in, const int* in_sizes, int n_in,
                              void* d_out, int out_size, void* d_ws, size_t ws_size,
                              hipStream_t stream) {
  (void)in_sizes; (void)n_in; (void)out_size; (void)ws_size;
  const float* x   = (const float*)d_in[0];
  const float* wq  = (const float*)d_in[1];
  const float* bq  = (const float*)d_in[2];
  const float* wk  = (const float*)d_in[3];
  const float* bk  = (const float*)d_in[4];
  const float* wv  = (const float*)d_in[5];
  const float* bv  = (const float*)d_in[6];
  const float* adj = (const float*)d_in[7];
  const float* w1  = (const float*)d_in[8];
  const float* b1  = (const float*)d_in[9];
  const float* lng = (const float*)d_in[10];
  const float* lnb = (const float*)d_in[11];
  const float* w2  = (const float*)d_in[12];
  const float* b2  = (const float*)d_in[13];

  const size_t BND = (size_t)MTOT * DD;  // 8,388,608
  float* outp  = (float*)d_out;          // [MTOT][256] (written by final w2 gemm)
  float* attnp = outp + BND;             // [MTOT][1024] (X splits -> keys+attn)

  // X1/X2 live in the attn scratch region (dead before scores writes keys)
  _Float16* X1 = (_Float16*)attnp;
  _Float16* X2 = X1 + BND;

  _Float16* Q1 = (_Float16*)d_ws;   // ~85 MB total ws use (proven available)
  _Float16* Q2 = Q1 + BND;
  _Float16* K1 = Q2 + BND;
  _Float16* K2 = K1 + BND;
  _Float16* WT = K2 + BND;          // [5][2][65536]
  _Float16* V16 = WT + 5 * 131072;  // fp16 V (16.78 MB)

  _Float16* M1 = Q1;          // reuse after topk (wave reads own Q row first)
  _Float16* H16 = (_Float16*)K1;  // reuse K1 region after topk (16 MB)
  _Float16* H1 = Q1;          // reuse after w1 consumed M1

  const dim3 blk(256);

  prep_w<<<dim3(1280), blk, 0, stream>>>(wq, wk, wv, w1, w2, WT);
  prep_x<<<dim3(4096), blk, 0, stream>>>(x, X1, X2);
  gemm_qkv<<<dim3(1536), blk, 0, stream>>>(X1, X2, WT, bq, bk, bv, Q1, Q2, K1, K2, V16);
  gemm_split<2><<<dim3(2048), blk, 0, stream>>>(Q1, K1, K2, adj, nullptr, attnp, nullptr);
  topk_softmax_msg<<<dim3(MTOT / 4), blk, 0, stream>>>(attnp, V16, Q1, Q2, K1, K2, adj, M1);
  gemm_split<0><<<dim3(2, 256), blk, 0, stream>>>(M1, WT + 3 * 131072, WT + 3 * 131072 + 65536,
                                                  b1, nullptr, nullptr, H16);
  ln_relu<<<dim3(MTOT / 4), blk, 0, stream>>>(H16, lng, lnb, H1);
  gemm_split<1><<<dim3(2, 256), blk, 0, stream>>>(H1, WT + 4 * 131072, WT + 4 * 131072 + 65536,
                                                  b2, V16, outp, nullptr);
}

// Round 13
// 310.899 us; speedup vs baseline: 1.0422x; 1.0422x over previous
//
#include <hip/hip_runtime.h>
#include <cstdint>

#define NB 32
#define NNODES 1024
#define DD 256
#define KNB 64
#define MTOT (NB * NNODES)  // 32768

// Scaling: activations stored as split(64*a), weights as split(1024*w).
// acc = sum (64a)(1024w) = 65536 * a.w  -> epilogue * 1/65536.
// scores acc = (64q).(64k) = 4096 q.k -> q.k/16 = acc/65536 too.
#define INV65536 1.52587890625e-05f
// 16-bit key cell over [-8,8)
#define KCELL 2.44140625e-4f

typedef _Float16 half8 __attribute__((ext_vector_type(8)));
typedef _Float16 half4 __attribute__((ext_vector_type(4)));
typedef float f32x4 __attribute__((ext_vector_type(4)));

typedef __attribute__((address_space(3))) uint32_t lds_u32;
typedef __attribute__((address_space(1))) uint32_t glb_u32;

// 16B async global->LDS. LDS dest wave-uniform; HW adds lane*16.
__device__ __forceinline__ void gll16(const _Float16* g, _Float16* l) {
  __builtin_amdgcn_global_load_lds((const glb_u32*)g, (lds_u32*)l, 16, 0, 0);
}

__device__ __forceinline__ void split2(float v, _Float16& h, _Float16& l) {
  h = (_Float16)v;
  l = (_Float16)(v - (float)h);
}

// =====================================================================
// prep_w: W[k][n] fp32 -> W_T[n][k] fp16x2, scaled by 1024.
// =====================================================================
__global__ __launch_bounds__(256) void prep_w(const float* __restrict__ wq,
                                              const float* __restrict__ wk,
                                              const float* __restrict__ wv,
                                              const float* __restrict__ w1,
                                              const float* __restrict__ w2,
                                              _Float16* __restrict__ WT) {
  const int idx = blockIdx.x * 256 + threadIdx.x;  // < 5*65536
  const int wsel = idx >> 16;
  const int rem = idx & 65535;
  const int k = rem >> 8, n = rem & 255;
  const float* src = (wsel == 0) ? wq : (wsel == 1) ? wk : (wsel == 2) ? wv : (wsel == 3) ? w1 : w2;
  const float v = src[rem] * 1024.0f;
  _Float16 h1, h2;
  split2(v, h1, h2);
  WT[(size_t)wsel * 131072 + n * 256 + k] = h1;
  WT[(size_t)wsel * 131072 + 65536 + n * 256 + k] = h2;
}

// =====================================================================
// prep_x: x fp32 -> X1,X2 = split(64*x) fp16. 8 elems/thread, coalesced.
// =====================================================================
__global__ __launch_bounds__(256) void prep_x(const float* __restrict__ x,
                                              _Float16* __restrict__ X1,
                                              _Float16* __restrict__ X2) {
  const size_t i = ((size_t)blockIdx.x * 256 + threadIdx.x) * 8;
  const float4 a = *(const float4*)(x + i);
  const float4 bb = *(const float4*)(x + i + 4);
  const float vals[8] = {a.x, a.y, a.z, a.w, bb.x, bb.y, bb.z, bb.w};
  half8 h, l;
#pragma unroll
  for (int e = 0; e < 8; ++e) {
    _Float16 hh, ll;
    split2(vals[e] * 64.0f, hh, ll);
    h[e] = hh;
    l[e] = ll;
  }
  *(half8*)(X1 + i) = h;
  *(half8*)(X2 + i) = l;
}

// LDS tile layout: [128 rows][8 chunks of 8 halfs], chunk XOR-swizzled by (row&7)
#define SWZ_OFF(r, cc) ((r) * 64 + (((cc) ^ ((r)&7)) << 3))

// =====================================================================
// gemm_qkv: A=X1/X2 pre-split, B=WT, all via global_load_lds.
// Q,K: 3 products (selection-critical). V: 1 product -> fp16 only.
// Grid 1D 1536, XCD-swizzled: 6 sibling blocks (same m-rows) per XCD.
// =====================================================================
__global__ __launch_bounds__(256) void gemm_qkv(const _Float16* __restrict__ X1,
                                                const _Float16* __restrict__ X2,
                                                const _Float16* __restrict__ WT,
                                                const float* __restrict__ bq,
                                                const float* __restrict__ bk,
                                                const float* __restrict__ bv,
                                                _Float16* __restrict__ Q1, _Float16* __restrict__ Q2,
                                                _Float16* __restrict__ K1, _Float16* __restrict__ K2,
                                                _Float16* __restrict__ V16) {
  __shared__ _Float16 sm[4 * 8192];
  _Float16* sA1 = sm;
  _Float16* sA2 = sm + 8192;
  _Float16* sB1 = sm + 16384;
  _Float16* sB2 = sm + 24576;

  const int tid = threadIdx.x;
  const int lane = tid & 63, w = tid >> 6;
  const int r16 = lane & 15, kg = lane >> 4;
  const int rsub = lane >> 3, csub = lane & 7;
  const int wm = (w >> 1) * 64, wn = (w & 1) * 64;

  // XCD swizzle: id%8 = XCD; 6 siblings (j=0..5) of each m-tile share id%8
  const int id = blockIdx.x;
  const int c8 = id & 7, t = id >> 3;   // t in 0..191
  const int gy = (t / 6) * 8 + c8;      // m-tile 0..255
  const int j6 = t % 6;
  const int wsel = j6 >> 1;
  const int n0 = (j6 & 1) * 128;
  const int m0 = gy * 128;
  const bool full = (wsel != 2);  // Q,K need 3 products; V needs 1

  const _Float16* pB1 = WT + (size_t)wsel * 131072;
  const _Float16* pB2 = pB1 + 65536;

  f32x4 acc[4][4];
#pragma unroll
  for (int i = 0; i < 4; ++i)
#pragma unroll
    for (int j = 0; j < 4; ++j) acc[i][j] = f32x4{0.f, 0.f, 0.f, 0.f};

  for (int k0 = 0; k0 < DD; k0 += 64) {
    __syncthreads();
#pragma unroll
    for (int it = 0; it < 4; ++it) {
      const int r = (w << 5) + (it << 3) + rsub;
      const int swz = ((csub ^ (r & 7)) << 3);
      const int ldso = (w << 11) + (it << 9);
      gll16(X1 + (size_t)(m0 + r) * DD + k0 + swz, sA1 + ldso);
      gll16(pB1 + (size_t)(n0 + r) * DD + k0 + swz, sB1 + ldso);
      if (full) {
        gll16(X2 + (size_t)(m0 + r) * DD + k0 + swz, sA2 + ldso);
        gll16(pB2 + (size_t)(n0 + r) * DD + k0 + swz, sB2 + ldso);
      }
    }
    __syncthreads();

#pragma unroll
    for (int s = 0; s < 2; ++s) {
      half8 aA[4], aB[4], bA[4], bB[4];
#pragma unroll
      for (int mi = 0; mi < 4; ++mi) {
        const int off = SWZ_OFF(wm + mi * 16 + r16, s * 4 + kg);
        aA[mi] = *(const half8*)(sA1 + off);
      }
#pragma unroll
      for (int nj = 0; nj < 4; ++nj) {
        const int off = SWZ_OFF(wn + nj * 16 + r16, s * 4 + kg);
        bA[nj] = *(const half8*)(sB1 + off);
      }
      if (full) {
#pragma unroll
        for (int mi = 0; mi < 4; ++mi) {
          const int off = SWZ_OFF(wm + mi * 16 + r16, s * 4 + kg);
          aB[mi] = *(const half8*)(sA2 + off);
        }
#pragma unroll
        for (int nj = 0; nj < 4; ++nj) {
          const int off = SWZ_OFF(wn + nj * 16 + r16, s * 4 + kg);
          bB[nj] = *(const half8*)(sB2 + off);
        }
      }
#pragma unroll
      for (int mi = 0; mi < 4; ++mi)
#pragma unroll
        for (int nj = 0; nj < 4; ++nj) {
          acc[mi][nj] = __builtin_amdgcn_mfma_f32_16x16x32_f16(aA[mi], bA[nj], acc[mi][nj], 0, 0, 0);
          if (full) {
            acc[mi][nj] = __builtin_amdgcn_mfma_f32_16x16x32_f16(aA[mi], bB[nj], acc[mi][nj], 0, 0, 0);
            acc[mi][nj] = __builtin_amdgcn_mfma_f32_16x16x32_f16(aB[mi], bA[nj], acc[mi][nj], 0, 0, 0);
          }
        }
    }
  }

  const float* bsel = (wsel == 0) ? bq : (wsel == 1) ? bk : bv;
  _Float16* P1 = (wsel == 0) ? Q1 : K1;
  _Float16* P2 = (wsel == 0) ? Q2 : K2;
#pragma unroll
  for (int mi = 0; mi < 4; ++mi)
#pragma unroll
    for (int nj = 0; nj < 4; ++nj) {
      const int col = n0 + wn + nj * 16 + r16;
#pragma unroll
      for (int j = 0; j < 4; ++j) {
        const int rr = m0 + wm + mi * 16 + kg * 4 + j;
        if (wsel == 2) {
          V16[(size_t)rr * DD + col] = (_Float16)(acc[mi][nj][j] * INV65536 + bsel[col]);
        } else {
          // store 64*Q = acc/1024 + 64*bias
          const float qv = acc[mi][nj][j] * (1.0f / 1024.0f) + 64.0f * bsel[col];
          _Float16 h1, h2;
          split2(qv, h1, h2);
          P1[(size_t)rr * DD + col] = h1;
          P2[(size_t)rr * DD + col] = h2;
        }
      }
    }
}

// =====================================================================
// gemm_split<EPI>: A single-split fp16, B pre-split fp16x2 (NT).
// EPI 0: H16 = fp16(acc/65536 + bias)      (w1 -> H16), 2 products
// EPI 1: C = acc/65536 + bias + resid16    (w2 -> out), 2 products
// EPI 2: scores -> u16 keys (bytes 2048..4095 of each attn row's 4KB),
//        2 products; grid 1D 2048 XCD-swizzled (batch -> one XCD so
//        K_b stays L2-resident; keeps r7's proven direct u16 epilogue).
// =====================================================================
template <int EPI>
__global__ __launch_bounds__(256) void gemm_split(const _Float16* __restrict__ A1,
                                                  const _Float16* __restrict__ B1g,
                                                  const _Float16* __restrict__ B2g,
                                                  const float* __restrict__ bias,
                                                  const _Float16* __restrict__ resid16,
                                                  float* __restrict__ C,
                                                  _Float16* __restrict__ C16) {
  __shared__ _Float16 sm[3 * 8192];
  _Float16* sA1 = sm;
  _Float16* sB1 = sm + 8192;
  _Float16* sB2 = sm + 16384;

  const int tid = threadIdx.x;
  const int lane = tid & 63, w = tid >> 6;
  const int r16 = lane & 15, kg = lane >> 4;
  const int rsub = lane >> 3, csub = lane & 7;
  const int wm = (w >> 1) * 64, wn = (w & 1) * 64;

  int n0, m0;
  if (EPI == 2) {
    // XCD swizzle: batch Bb's 64 blocks share id%8 = one XCD
    const int id = blockIdx.x;
    const int c8 = id & 7, t = id >> 3;   // t in 0..255
    const int Bb = ((t >> 6) << 3) + c8;  // batch 0..31
    const int r = (t >> 3) & 7;           // m sub-tile
    const int bx = t & 7;                 // n tile
    n0 = bx * 128;
    m0 = (Bb * 8 + r) * 128;
  } else {
    n0 = blockIdx.x * 128;
    m0 = blockIdx.y * 128;
  }

  const _Float16* pB1 = B1g;
  const _Float16* pB2 = B2g;
  if (EPI == 2) {
    const size_t boff = (size_t)(m0 >> 10) * NNODES * DD;
    pB1 += boff;
    pB2 += boff;
  }

  f32x4 acc[4][4];
#pragma unroll
  for (int i = 0; i < 4; ++i)
#pragma unroll
    for (int j = 0; j < 4; ++j) acc[i][j] = f32x4{0.f, 0.f, 0.f, 0.f};

  for (int k0 = 0; k0 < DD; k0 += 64) {
    __syncthreads();
#pragma unroll
    for (int it = 0; it < 4; ++it) {
      const int r = (w << 5) + (it << 3) + rsub;
      const int swz = ((csub ^ (r & 7)) << 3);
      const int ldso = (w << 11) + (it << 9);
      gll16(A1 + (size_t)(m0 + r) * DD + k0 + swz, sA1 + ldso);
      gll16(pB1 + (size_t)(n0 + r) * DD + k0 + swz, sB1 + ldso);
      gll16(pB2 + (size_t)(n0 + r) * DD + k0 + swz, sB2 + ldso);
    }
    __syncthreads();

#pragma unroll
    for (int s = 0; s < 2; ++s) {
      half8 aA[4], bA[4], bB[4];
#pragma unroll
      for (int mi = 0; mi < 4; ++mi) {
        const int off = SWZ_OFF(wm + mi * 16 + r16, s * 4 + kg);
        aA[mi] = *(const half8*)(sA1 + off);
      }
#pragma unroll
      for (int nj = 0; nj < 4; ++nj) {
        const int off = SWZ_OFF(wn + nj * 16 + r16, s * 4 + kg);
        bA[nj] = *(const half8*)(sB1 + off);
        bB[nj] = *(const half8*)(sB2 + off);
      }
#pragma unroll
      for (int mi = 0; mi < 4; ++mi)
#pragma unroll
        for (int nj = 0; nj < 4; ++nj) {
          acc[mi][nj] = __builtin_amdgcn_mfma_f32_16x16x32_f16(aA[mi], bA[nj], acc[mi][nj], 0, 0, 0);
          acc[mi][nj] = __builtin_amdgcn_mfma_f32_16x16x32_f16(aA[mi], bB[nj], acc[mi][nj], 0, 0, 0);
        }
    }
  }

#pragma unroll
  for (int mi = 0; mi < 4; ++mi)
#pragma unroll
    for (int nj = 0; nj < 4; ++nj) {
      const int col = n0 + wn + nj * 16 + r16;
#pragma unroll
      for (int j = 0; j < 4; ++j) {
        const int rr = m0 + wm + mi * 16 + kg * 4 + j;
        const float v = acc[mi][nj][j] * INV65536;
        if (EPI == 2) {
          const float sv = v + bias[(size_t)(rr & (NNODES - 1)) * NNODES + col];
          const float f = fminf(fmaxf((sv + 8.0f) * 4096.0f, 0.0f), 65535.0f);
          uint16_t* kbase = (uint16_t*)((char*)C + (size_t)rr * 4096 + 2048);
          kbase[col] = (uint16_t)(unsigned)f;
        } else if (EPI == 0) {
          C16[(size_t)rr * DD + col] = (_Float16)(v + bias[col]);
        } else {
          C[(size_t)rr * DD + col] = v + bias[col] + (float)resid16[(size_t)rr * DD + col];
        }
      }
    }
}

// =====================================================================
// Top-64 from u16 keys + masked softmax + sparse messages. One wave/row.
// No occupancy attribute: r12 proved this kernel is TLP-hungry (4 waves/EU
// regressed 126->146); compiler's 8-waves/32-VGPR point is best.
// Slim fast path (r11): masks+counts only; position tracking in the rare
// slow path; softmax from integer keys. kx computed first so radix levels
// with cand > kx are skipped (provably cnt=0 -> exact).
// Band: hi key>=cur+5 (provably in), out key<cur-4 (provably out);
// candidates: exact fp32 recompute, jax tie semantics.
// =====================================================================
__global__ __launch_bounds__(256) void topk_softmax_msg(float* __restrict__ S,
                                                        const _Float16* __restrict__ V16,
                                                        const _Float16* __restrict__ Q1,
                                                        const _Float16* __restrict__ Q2,
                                                        const _Float16* __restrict__ K1,
                                                        const _Float16* __restrict__ K2,
                                                        const float* __restrict__ adj,
                                                        _Float16* __restrict__ M1) {
  const int tid = threadIdx.x;
  const int w = tid >> 6, lane = tid & 63;
  // XCD swizzle: batch = (t>>8)*8 + id%8 -> whole batch on one XCD
  const int id = blockIdx.x;            // 0..8191
  const int xcd = id & 7, t = id >> 3;  // t 0..1023
  const int b = (t >> 8) * 8 + xcd;     // batch 0..31
  const int row = b * NNODES + (t & 255) * 4 + w;
  const int m = row & (NNODES - 1);
  float* Srow = S + (size_t)row * NNODES;
  const uint16_t* krow = (const uint16_t*)((const char*)S + (size_t)row * 4096 + 2048);

  __shared__ float2 spair[4][KNB];  // (wgt, V16 row byte-offset bits)
  __shared__ int cidxs[4][32];
  __shared__ float cex[4][32];
  __shared__ int csel[4][32];

  if (lane < KNB) spair[w][lane] = make_float2(0.0f, __int_as_float(0));

  // load 16 keys: k[t] maps to col(t) = (t>>3)*512 + lane*8 + (t&7)
  const uint4 u0 = *(const uint4*)(krow + lane * 8);
  const uint4 u1 = *(const uint4*)(krow + 512 + lane * 8);
  int k[16];
  {
    const unsigned uu[8] = {u0.x, u0.y, u0.z, u0.w, u1.x, u1.y, u1.z, u1.w};
#pragma unroll
    for (int q = 0; q < 8; ++q) {
      k[q * 2] = (int)(uu[q] & 0xffffu);
      k[q * 2 + 1] = (int)(uu[q] >> 16);
    }
  }

  // wave-wide integer key max (softmax base + radix upper bound)
  int kx = k[0];
#pragma unroll
  for (int t2 = 1; t2 < 16; ++t2) kx = (k[t2] > kx) ? k[t2] : kx;
#pragma unroll
  for (int off = 32; off > 0; off >>= 1) {
    const int o = __shfl_xor(kx, off);
    kx = (o > kx) ? o : kx;
  }

  // radix-select 64th-largest key (16 bits); skip levels with cand > kx
  int cur = 0;
#pragma unroll 1
  for (int bit = 15; bit >= 0; --bit) {
    const int cand = cur | (1 << bit);
    if (cand > kx) continue;  // exact: no key >= cand, cnt would be 0
    int cnt = 0;
#pragma unroll
    for (int t2 = 0; t2 < 16; ++t2) cnt += (int)__popcll(__ballot(k[t2] >= cand));
    if (cnt >= KNB) cur = cand;
  }

  const int kHi = cur + 5;  // key >= kHi -> provably in top-64
  const int kLo = cur - 4;  // key <  kLo -> provably out

  // classification: masks + counts only (no position tracking)
  unsigned hm = 0u, cm = 0u;
  int nhi = 0, ncand = 0;
#pragma unroll
  for (int t2 = 0; t2 < 16; ++t2) {
    const bool hiv = (k[t2] >= kHi);
    const bool cdv = (!hiv) && (k[t2] >= kLo);
    if (hiv) hm |= (1u << t2);
    if (cdv) cm |= (1u << t2);
    nhi += (int)__popcll(__ballot(hiv));
    ncand += (int)__popcll(__ballot(cdv));
  }
  const int need = KNB - nhi;  // >= 1; nhi+ncand >= 64

  unsigned selm;
  if (ncand == need) {
    selm = hm | cm;  // fast path (vast majority of rows)
  } else {
    // slow path: compact candidates in index order, exact fp32 recompute
    const unsigned long long ltm = (1ull << lane) - 1ull;
    int cpos[16];
    int nc0 = 0;
#pragma unroll
    for (int g = 0; g < 2; ++g) {
      bool cdv8[8];
      unsigned long long mcv[8];
#pragma unroll
      for (int e = 0; e < 8; ++e) {
        cdv8[e] = (cm >> (g * 8 + e)) & 1u;
        mcv[e] = __ballot(cdv8[e]);
      }
      int below = 0, tot = 0;
#pragma unroll
      for (int e = 0; e < 8; ++e) {
        below += (int)__popcll(mcv[e] & ltm);
        tot += (int)__popcll(mcv[e]);
      }
      int own = 0;
#pragma unroll
      for (int e = 0; e < 8; ++e) {
        const int t2 = g * 8 + e;
        cpos[t2] = -1;
        if (cdv8[e]) {
          const int p2 = nc0 + below + own;
          cpos[t2] = p2;
          if (p2 < 32) cidxs[w][p2] = g * 512 + lane * 8 + e;
          ++own;
        }
      }
      nc0 += tot;
    }
    const int nc = (ncand <= 32) ? ncand : 32;
    const int nd = (need <= nc) ? need : nc;
    const size_t qoff = (size_t)row * DD + lane * 4;
    const half4 q1v = *(const half4*)(Q1 + qoff);
    const half4 q2v = *(const half4*)(Q2 + qoff);
    float qf[4];
#pragma unroll
    for (int e = 0; e < 4; ++e) qf[e] = (float)q1v[e] + (float)q2v[e];
    const float* adjrow = adj + (size_t)m * NNODES;
#pragma unroll 2
    for (int t2 = 0; t2 < nc; ++t2) {
      const int j = cidxs[w][t2];
      const size_t koff = ((size_t)b * NNODES + j) * DD + lane * 4;
      const half4 k1v = *(const half4*)(K1 + koff);
      const half4 k2v = *(const half4*)(K2 + koff);
      float part = 0.0f;
#pragma unroll
      for (int e = 0; e < 4; ++e) part = fmaf(qf[e], (float)k1v[e] + (float)k2v[e], part);
#pragma unroll
      for (int off = 32; off > 0; off >>= 1) part += __shfl_xor(part, off);
      if (lane == 0) cex[w][t2] = part * INV65536 + adjrow[j];
    }
    if (lane < nc) {
      const float et = cex[w][lane];
      int rank = 0;
      for (int u = 0; u < nc; ++u) {
        const float eu = cex[w][u];
        rank += (eu > et || (eu == et && u < lane)) ? 1 : 0;
      }
      csel[w][lane] = (rank < nd) ? 1 : 0;
    }
    selm = hm;
#pragma unroll
    for (int t2 = 0; t2 < 16; ++t2) {
      if (((cm >> t2) & 1u) && cpos[t2] >= 0 && cpos[t2] < 32 && csel[w][cpos[t2]]) selm |= (1u << t2);
    }
  }

  // softmax over selected, directly from integer keys
  float p[16];
  float sum = 0.0f;
#pragma unroll
  for (int t2 = 0; t2 < 16; ++t2) {
    p[t2] = __expf((float)(k[t2] - kx) * KCELL);
    if ((selm >> t2) & 1u) sum += p[t2];
  }
#pragma unroll
  for (int off = 32; off > 0; off >>= 1) sum += __shfl_xor(sum, off);
  const float inv = 1.0f / sum;

  // attn write (overwrites full 4KB row incl. key half) + ordered compaction
  const unsigned long long ltmask = (1ull << lane) - 1ull;
  int run = 0;
#pragma unroll
  for (int g = 0; g < 2; ++g) {
    bool sel8[8];
    unsigned long long ms[8];
#pragma unroll
    for (int e = 0; e < 8; ++e) {
      sel8[e] = (selm >> (g * 8 + e)) & 1u;
      ms[e] = __ballot(sel8[e]);
    }
    int below = 0, tot = 0;
#pragma unroll
    for (int e = 0; e < 8; ++e) {
      below += (int)__popcll(ms[e] & ltmask);
      tot += (int)__popcll(ms[e]);
    }
    float ow[8];
    int own = 0;
#pragma unroll
    for (int e = 0; e < 8; ++e) {
      const int t2 = g * 8 + e;
      const float aw = sel8[e] ? p[t2] * inv : 0.0f;
      ow[e] = aw;
      if (sel8[e]) {
        const int pos = run + below + own;
        // store V16 row byte-offset: col * DD * 2
        if (pos < KNB)
          spair[w][pos] = make_float2(aw, __int_as_float((g * 512 + lane * 8 + e) * (DD * 2)));
        ++own;
      }
    }
    float* dst = Srow + g * 512 + lane * 8;
    *(float4*)(dst) = make_float4(ow[0], ow[1], ow[2], ow[3]);
    *(float4*)(dst + 4) = make_float4(ow[4], ow[5], ow[6], ow[7]);
    run += tot;
  }

  // messages: lane owns output dims [lane*4, lane*4+4)
  float4 acc = {0.0f, 0.0f, 0.0f, 0.0f};
  const char* Vbase = (const char*)(V16 + (size_t)b * NNODES * DD) + lane * 8;
#pragma unroll 4
  for (int t2 = 0; t2 < KNB; ++t2) {
    const float2 pr = spair[w][t2];
    const int off = __float_as_int(pr.y);
    const half4 vv = *(const half4*)(Vbase + off);
    acc.x = fmaf(pr.x, (float)vv[0], acc.x);
    acc.y = fmaf(pr.x, (float)vv[1], acc.y);
    acc.z = fmaf(pr.x, (float)vv[2], acc.z);
    acc.w = fmaf(pr.x, (float)vv[3], acc.w);
  }
  // M stored as single fp16(64*m) -- downstream w1 runs 2-product
  half4 m1;
  m1[0] = (_Float16)(acc.x * 64.0f);
  m1[1] = (_Float16)(acc.y * 64.0f);
  m1[2] = (_Float16)(acc.z * 64.0f);
  m1[3] = (_Float16)(acc.w * 64.0f);
  *(half4*)(M1 + (size_t)row * DD + lane * 4) = m1;
}

// =====================================================================
// LayerNorm + ReLU: H16 fp16 -> single fp16(64*y). Wave per row, no LDS.
// =====================================================================
__global__ __launch_bounds__(256) void ln_relu(const _Float16* __restrict__ H16,
                                               const float* __restrict__ g,
                                               const float* __restrict__ bta,
                                               _Float16* __restrict__ H1) {
  const int tid = threadIdx.x;
  const int row = blockIdx.x * 4 + (tid >> 6);
  const int lane = tid & 63;
  const half4 hv = *(const half4*)(H16 + (size_t)row * DD + lane * 4);
  float h[4];
#pragma unroll
  for (int j = 0; j < 4; ++j) h[j] = (float)hv[j];

  float s = h[0] + h[1] + h[2] + h[3];
#pragma unroll
  for (int off = 32; off > 0; off >>= 1) s += __shfl_xor(s, off);
  const float mu = s * (1.0f / 256.0f);

  float d[4], sq = 0.0f;
#pragma unroll
  for (int j = 0; j < 4; ++j) {
    d[j] = h[j] - mu;
    sq += d[j] * d[j];
  }
#pragma unroll
  for (int off = 32; off > 0; off >>= 1) sq += __shfl_xor(sq, off);
  const float rstd = 1.0f / sqrtf(sq * (1.0f / 256.0f) + 1e-5f);

  const float4 gv = *(const float4*)(g + lane * 4);
  const float4 bv = *(const float4*)(bta + lane * 4);
  const float gg[4] = {gv.x, gv.y, gv.z, gv.w};
  const float bb[4] = {bv.x, bv.y, bv.z, bv.w};
  half4 o;
#pragma unroll
  for (int j = 0; j < 4; ++j) {
    const float y = fmaxf(d[j] * rstd * gg[j] + bb[j], 0.0f);
    o[j] = (_Float16)(y * 64.0f);
  }
  *(half4*)(H1 + (size_t)row * DD + lane * 4) = o;
}

// =====================================================================
// Host launch
// =====================================================================
extern "C" void kernel_launch(void* const* d_in, const int* in_sizes, int n_in,
                              void* d_out, int out_size, void* d_ws, size_t ws_size,
                              hipStream_t stream) {
  (void)in_sizes; (void)n_in; (void)out_size; (void)ws_size;
  const float* x   = (const float*)d_in[0];
  const float* wq  = (const float*)d_in[1];
  const float* bq  = (const float*)d_in[2];
  const float* wk  = (const float*)d_in[3];
  const float* bk  = (const float*)d_in[4];
  const float* wv  = (const float*)d_in[5];
  const float* bv  = (const float*)d_in[6];
  const float* adj = (const float*)d_in[7];
  const float* w1  = (const float*)d_in[8];
  const float* b1  = (const float*)d_in[9];
  const float* lng = (const float*)d_in[10];
  const float* lnb = (const float*)d_in[11];
  const float* w2  = (const float*)d_in[12];
  const float* b2  = (const float*)d_in[13];

  const size_t BND = (size_t)MTOT * DD;  // 8,388,608
  float* outp  = (float*)d_out;          // [MTOT][256] (written by final w2 gemm)
  float* attnp = outp + BND;             // [MTOT][1024] (X splits -> keys+attn)

  // X1/X2 live in the attn scratch region (dead before scores writes keys)
  _Float16* X1 = (_Float16*)attnp;
  _Float16* X2 = X1 + BND;

  _Float16* Q1 = (_Float16*)d_ws;   // ~85 MB total ws use (proven available)
  _Float16* Q2 = Q1 + BND;
  _Float16* K1 = Q2 + BND;
  _Float16* K2 = K1 + BND;
  _Float16* WT = K2 + BND;          // [5][2][65536]
  _Float16* V16 = WT + 5 * 131072;  // fp16 V (16.78 MB)

  _Float16* M1 = Q1;          // reuse after topk (wave reads own Q row first)
  _Float16* H16 = (_Float16*)K1;  // reuse K1 region after topk (16 MB)
  _Float16* H1 = Q1;          // reuse after w1 consumed M1

  const dim3 blk(256);

  prep_w<<<dim3(1280), blk, 0, stream>>>(wq, wk, wv, w1, w2, WT);
  prep_x<<<dim3(4096), blk, 0, stream>>>(x, X1, X2);
  gemm_qkv<<<dim3(1536), blk, 0, stream>>>(X1, X2, WT, bq, bk, bv, Q1, Q2, K1, K2, V16);
  gemm_split<2><<<dim3(2048), blk, 0, stream>>>(Q1, K1, K2, adj, nullptr, attnp, nullptr);
  topk_softmax_msg<<<dim3(MTOT / 4), blk, 0, stream>>>(attnp, V16, Q1, Q2, K1, K2, adj, M1);
  gemm_split<0><<<dim3(2, 256), blk, 0, stream>>>(M1, WT + 3 * 131072, WT + 3 * 131072 + 65536,
                                                  b1, nullptr, nullptr, H16);
  ln_relu<<<dim3(MTOT / 4), blk, 0, stream>>>(H16, lng, lnb, H1);
  gemm_split<1><<<dim3(2, 256), blk, 0, stream>>>(H1, WT + 4 * 131072, WT + 4 * 131072 + 65536,
                                                  b2, V16, outp, nullptr);
}

// Round 14
// 301.669 us; speedup vs baseline: 1.0741x; 1.0306x over previous
//
#include <hip/hip_runtime.h>
#include <cstdint>

#define NB 32
#define NNODES 1024
#define DD 256
#define KNB 64
#define MTOT (NB * NNODES)  // 32768

// Scaling: activations stored as split(64*a), weights as split(1024*w).
// acc = sum (64a)(1024w) = 65536 * a.w  -> epilogue * 1/65536.
// scores acc = (64q).(64k) = 4096 q.k -> q.k/16 = acc/65536 too.
#define INV65536 1.52587890625e-05f
// 16-bit key cell over [-8,8)
#define KCELL 2.44140625e-4f

typedef _Float16 half8 __attribute__((ext_vector_type(8)));
typedef _Float16 half4 __attribute__((ext_vector_type(4)));
typedef float f32x4 __attribute__((ext_vector_type(4)));

typedef __attribute__((address_space(3))) uint32_t lds_u32;
typedef __attribute__((address_space(1))) uint32_t glb_u32;

// 16B async global->LDS. LDS dest wave-uniform; HW adds lane*16.
__device__ __forceinline__ void gll16(const _Float16* g, _Float16* l) {
  __builtin_amdgcn_global_load_lds((const glb_u32*)g, (lds_u32*)l, 16, 0, 0);
}

__device__ __forceinline__ void split2(float v, _Float16& h, _Float16& l) {
  h = (_Float16)v;
  l = (_Float16)(v - (float)h);
}

// =====================================================================
// prep_wx: fused weight + activation pre-split (one launch).
// blocks [0,4096): x fp32 -> X1,X2 = split(64*x), 8 elems/thread.
// blocks [4096,5376): W[k][n] fp32 -> W_T[n][k] fp16x2, scaled by 1024.
// =====================================================================
__global__ __launch_bounds__(256) void prep_wx(const float* __restrict__ x,
                                               _Float16* __restrict__ X1,
                                               _Float16* __restrict__ X2,
                                               const float* __restrict__ wq,
                                               const float* __restrict__ wk,
                                               const float* __restrict__ wv,
                                               const float* __restrict__ w1,
                                               const float* __restrict__ w2,
                                               _Float16* __restrict__ WT) {
  if (blockIdx.x < 4096) {
    const size_t i = ((size_t)blockIdx.x * 256 + threadIdx.x) * 8;
    const float4 a = *(const float4*)(x + i);
    const float4 bb = *(const float4*)(x + i + 4);
    const float vals[8] = {a.x, a.y, a.z, a.w, bb.x, bb.y, bb.z, bb.w};
    half8 h, l;
#pragma unroll
    for (int e = 0; e < 8; ++e) {
      _Float16 hh, ll;
      split2(vals[e] * 64.0f, hh, ll);
      h[e] = hh;
      l[e] = ll;
    }
    *(half8*)(X1 + i) = h;
    *(half8*)(X2 + i) = l;
  } else {
    const int idx = (blockIdx.x - 4096) * 256 + threadIdx.x;  // < 5*65536
    const int wsel = idx >> 16;
    const int rem = idx & 65535;
    const int k = rem >> 8, n = rem & 255;
    const float* src = (wsel == 0) ? wq : (wsel == 1) ? wk : (wsel == 2) ? wv : (wsel == 3) ? w1 : w2;
    const float v = src[rem] * 1024.0f;
    _Float16 h1, h2;
    split2(v, h1, h2);
    WT[(size_t)wsel * 131072 + n * 256 + k] = h1;
    WT[(size_t)wsel * 131072 + 65536 + n * 256 + k] = h2;
  }
}

// LDS tile layout: [128 rows][8 chunks of 8 halfs], chunk XOR-swizzled by (row&7)
#define SWZ_OFF(r, cc) ((r) * 64 + (((cc) ^ ((r)&7)) << 3))

// =====================================================================
// gemm_qkv: A=X1/X2 pre-split, B=WT, all via global_load_lds.
// Q,K: 3 products (selection-critical). V: 1 product -> fp16 only.
// Grid 1D 1536, XCD-swizzled: 6 sibling blocks (same m-rows) per XCD.
// =====================================================================
__global__ __launch_bounds__(256) void gemm_qkv(const _Float16* __restrict__ X1,
                                                const _Float16* __restrict__ X2,
                                                const _Float16* __restrict__ WT,
                                                const float* __restrict__ bq,
                                                const float* __restrict__ bk,
                                                const float* __restrict__ bv,
                                                _Float16* __restrict__ Q1, _Float16* __restrict__ Q2,
                                                _Float16* __restrict__ K1, _Float16* __restrict__ K2,
                                                _Float16* __restrict__ V16) {
  __shared__ _Float16 sm[4 * 8192];
  _Float16* sA1 = sm;
  _Float16* sA2 = sm + 8192;
  _Float16* sB1 = sm + 16384;
  _Float16* sB2 = sm + 24576;

  const int tid = threadIdx.x;
  const int lane = tid & 63, w = tid >> 6;
  const int r16 = lane & 15, kg = lane >> 4;
  const int rsub = lane >> 3, csub = lane & 7;
  const int wm = (w >> 1) * 64, wn = (w & 1) * 64;

  // XCD swizzle: id%8 = XCD; 6 siblings (j=0..5) of each m-tile share id%8
  const int id = blockIdx.x;
  const int c8 = id & 7, t = id >> 3;   // t in 0..191
  const int gy = (t / 6) * 8 + c8;      // m-tile 0..255
  const int j6 = t % 6;
  const int wsel = j6 >> 1;
  const int n0 = (j6 & 1) * 128;
  const int m0 = gy * 128;
  const bool full = (wsel != 2);  // Q,K need 3 products; V needs 1

  const _Float16* pB1 = WT + (size_t)wsel * 131072;
  const _Float16* pB2 = pB1 + 65536;

  f32x4 acc[4][4];
#pragma unroll
  for (int i = 0; i < 4; ++i)
#pragma unroll
    for (int j = 0; j < 4; ++j) acc[i][j] = f32x4{0.f, 0.f, 0.f, 0.f};

  for (int k0 = 0; k0 < DD; k0 += 64) {
    __syncthreads();
#pragma unroll
    for (int it = 0; it < 4; ++it) {
      const int r = (w << 5) + (it << 3) + rsub;
      const int swz = ((csub ^ (r & 7)) << 3);
      const int ldso = (w << 11) + (it << 9);
      gll16(X1 + (size_t)(m0 + r) * DD + k0 + swz, sA1 + ldso);
      gll16(pB1 + (size_t)(n0 + r) * DD + k0 + swz, sB1 + ldso);
      if (full) {
        gll16(X2 + (size_t)(m0 + r) * DD + k0 + swz, sA2 + ldso);
        gll16(pB2 + (size_t)(n0 + r) * DD + k0 + swz, sB2 + ldso);
      }
    }
    __syncthreads();

#pragma unroll
    for (int s = 0; s < 2; ++s) {
      half8 aA[4], aB[4], bA[4], bB[4];
#pragma unroll
      for (int mi = 0; mi < 4; ++mi) {
        const int off = SWZ_OFF(wm + mi * 16 + r16, s * 4 + kg);
        aA[mi] = *(const half8*)(sA1 + off);
      }
#pragma unroll
      for (int nj = 0; nj < 4; ++nj) {
        const int off = SWZ_OFF(wn + nj * 16 + r16, s * 4 + kg);
        bA[nj] = *(const half8*)(sB1 + off);
      }
      if (full) {
#pragma unroll
        for (int mi = 0; mi < 4; ++mi) {
          const int off = SWZ_OFF(wm + mi * 16 + r16, s * 4 + kg);
          aB[mi] = *(const half8*)(sA2 + off);
        }
#pragma unroll
        for (int nj = 0; nj < 4; ++nj) {
          const int off = SWZ_OFF(wn + nj * 16 + r16, s * 4 + kg);
          bB[nj] = *(const half8*)(sB2 + off);
        }
      }
#pragma unroll
      for (int mi = 0; mi < 4; ++mi)
#pragma unroll
        for (int nj = 0; nj < 4; ++nj) {
          acc[mi][nj] = __builtin_amdgcn_mfma_f32_16x16x32_f16(aA[mi], bA[nj], acc[mi][nj], 0, 0, 0);
          if (full) {
            acc[mi][nj] = __builtin_amdgcn_mfma_f32_16x16x32_f16(aA[mi], bB[nj], acc[mi][nj], 0, 0, 0);
            acc[mi][nj] = __builtin_amdgcn_mfma_f32_16x16x32_f16(aB[mi], bA[nj], acc[mi][nj], 0, 0, 0);
          }
        }
    }
  }

  const float* bsel = (wsel == 0) ? bq : (wsel == 1) ? bk : bv;
  _Float16* P1 = (wsel == 0) ? Q1 : K1;
  _Float16* P2 = (wsel == 0) ? Q2 : K2;
#pragma unroll
  for (int mi = 0; mi < 4; ++mi)
#pragma unroll
    for (int nj = 0; nj < 4; ++nj) {
      const int col = n0 + wn + nj * 16 + r16;
#pragma unroll
      for (int j = 0; j < 4; ++j) {
        const int rr = m0 + wm + mi * 16 + kg * 4 + j;
        if (wsel == 2) {
          V16[(size_t)rr * DD + col] = (_Float16)(acc[mi][nj][j] * INV65536 + bsel[col]);
        } else {
          // store 64*Q = acc/1024 + 64*bias
          const float qv = acc[mi][nj][j] * (1.0f / 1024.0f) + 64.0f * bsel[col];
          _Float16 h1, h2;
          split2(qv, h1, h2);
          P1[(size_t)rr * DD + col] = h1;
          P2[(size_t)rr * DD + col] = h2;
        }
      }
    }
}

// =====================================================================
// gemm_split<EPI>: A single-split fp16, B pre-split fp16x2 (NT).
// EPI 0: H16 = fp16(acc/65536 + bias)      (w1 -> H16), 2 products
// EPI 1: C = acc/65536 + bias + resid16    (w2 -> out), 2 products
// EPI 2: scores -> u16 keys (bytes 2048..4095 of each attn row's 4KB),
//        2 products; grid 1D 2048 XCD-swizzled (batch -> one XCD so
//        K_b stays L2-resident).
// =====================================================================
template <int EPI>
__global__ __launch_bounds__(256) void gemm_split(const _Float16* __restrict__ A1,
                                                  const _Float16* __restrict__ B1g,
                                                  const _Float16* __restrict__ B2g,
                                                  const float* __restrict__ bias,
                                                  const _Float16* __restrict__ resid16,
                                                  float* __restrict__ C,
                                                  _Float16* __restrict__ C16) {
  __shared__ _Float16 sm[3 * 8192];
  _Float16* sA1 = sm;
  _Float16* sB1 = sm + 8192;
  _Float16* sB2 = sm + 16384;

  const int tid = threadIdx.x;
  const int lane = tid & 63, w = tid >> 6;
  const int r16 = lane & 15, kg = lane >> 4;
  const int rsub = lane >> 3, csub = lane & 7;
  const int wm = (w >> 1) * 64, wn = (w & 1) * 64;

  int n0, m0;
  if (EPI == 2) {
    // XCD swizzle: batch Bb's 64 blocks share id%8 = one XCD
    const int id = blockIdx.x;
    const int c8 = id & 7, t = id >> 3;   // t in 0..255
    const int Bb = ((t >> 6) << 3) + c8;  // batch 0..31
    const int r = (t >> 3) & 7;           // m sub-tile
    const int bx = t & 7;                 // n tile
    n0 = bx * 128;
    m0 = (Bb * 8 + r) * 128;
  } else {
    n0 = blockIdx.x * 128;
    m0 = blockIdx.y * 128;
  }

  const _Float16* pB1 = B1g;
  const _Float16* pB2 = B2g;
  if (EPI == 2) {
    const size_t boff = (size_t)(m0 >> 10) * NNODES * DD;
    pB1 += boff;
    pB2 += boff;
  }

  f32x4 acc[4][4];
#pragma unroll
  for (int i = 0; i < 4; ++i)
#pragma unroll
    for (int j = 0; j < 4; ++j) acc[i][j] = f32x4{0.f, 0.f, 0.f, 0.f};

  for (int k0 = 0; k0 < DD; k0 += 64) {
    __syncthreads();
#pragma unroll
    for (int it = 0; it < 4; ++it) {
      const int r = (w << 5) + (it << 3) + rsub;
      const int swz = ((csub ^ (r & 7)) << 3);
      const int ldso = (w << 11) + (it << 9);
      gll16(A1 + (size_t)(m0 + r) * DD + k0 + swz, sA1 + ldso);
      gll16(pB1 + (size_t)(n0 + r) * DD + k0 + swz, sB1 + ldso);
      gll16(pB2 + (size_t)(n0 + r) * DD + k0 + swz, sB2 + ldso);
    }
    __syncthreads();

#pragma unroll
    for (int s = 0; s < 2; ++s) {
      half8 aA[4], bA[4], bB[4];
#pragma unroll
      for (int mi = 0; mi < 4; ++mi) {
        const int off = SWZ_OFF(wm + mi * 16 + r16, s * 4 + kg);
        aA[mi] = *(const half8*)(sA1 + off);
      }
#pragma unroll
      for (int nj = 0; nj < 4; ++nj) {
        const int off = SWZ_OFF(wn + nj * 16 + r16, s * 4 + kg);
        bA[nj] = *(const half8*)(sB1 + off);
        bB[nj] = *(const half8*)(sB2 + off);
      }
#pragma unroll
      for (int mi = 0; mi < 4; ++mi)
#pragma unroll
        for (int nj = 0; nj < 4; ++nj) {
          acc[mi][nj] = __builtin_amdgcn_mfma_f32_16x16x32_f16(aA[mi], bA[nj], acc[mi][nj], 0, 0, 0);
          acc[mi][nj] = __builtin_amdgcn_mfma_f32_16x16x32_f16(aA[mi], bB[nj], acc[mi][nj], 0, 0, 0);
        }
    }
  }

#pragma unroll
  for (int mi = 0; mi < 4; ++mi)
#pragma unroll
    for (int nj = 0; nj < 4; ++nj) {
      const int col = n0 + wn + nj * 16 + r16;
#pragma unroll
      for (int j = 0; j < 4; ++j) {
        const int rr = m0 + wm + mi * 16 + kg * 4 + j;
        const float v = acc[mi][nj][j] * INV65536;
        if (EPI == 2) {
          const float sv = v + bias[(size_t)(rr & (NNODES - 1)) * NNODES + col];
          const float f = fminf(fmaxf((sv + 8.0f) * 4096.0f, 0.0f), 65535.0f);
          uint16_t* kbase = (uint16_t*)((char*)C + (size_t)rr * 4096 + 2048);
          kbase[col] = (uint16_t)(unsigned)f;
        } else if (EPI == 0) {
          C16[(size_t)rr * DD + col] = (_Float16)(v + bias[col]);
        } else {
          C[(size_t)rr * DD + col] = v + bias[col] + (float)resid16[(size_t)rr * DD + col];
        }
      }
    }
}

// =====================================================================
// Top-64 from u16 keys + masked softmax + sparse messages. One wave/row.
// REVERTED to the round-10 proven version (126 us, VGPR 32, occ 62%):
// r12/r13 showed any register-for-instructions trade loses to TLP here.
// Band: hi key>=cur+5 (provably in), out key<cur-4 (provably out).
// Candidates: exact fp32 recompute from split Q,K; jax tie semantics.
// =====================================================================
__global__ __launch_bounds__(256, 4) void topk_softmax_msg(float* __restrict__ S,
                                                           const _Float16* __restrict__ V16,
                                                           const _Float16* __restrict__ Q1,
                                                           const _Float16* __restrict__ Q2,
                                                           const _Float16* __restrict__ K1,
                                                           const _Float16* __restrict__ K2,
                                                           const float* __restrict__ adj,
                                                           _Float16* __restrict__ M1) {
  const int tid = threadIdx.x;
  const int w = tid >> 6, lane = tid & 63;
  // XCD swizzle: batch = (t>>8)*8 + id%8 -> whole batch on one XCD
  const int id = blockIdx.x;            // 0..8191
  const int xcd = id & 7, t = id >> 3;  // t 0..1023
  const int b = (t >> 8) * 8 + xcd;     // batch 0..31
  const int row = b * NNODES + (t & 255) * 4 + w;
  const int m = row & (NNODES - 1);
  float* Srow = S + (size_t)row * NNODES;
  const uint16_t* krow = (const uint16_t*)((const char*)S + (size_t)row * 4096 + 2048);

  __shared__ float2 spair[4][KNB];  // (wgt, V16 row byte-offset bits)
  __shared__ int cidxs[4][32];
  __shared__ float cex[4][32];
  __shared__ int csel[4][32];

  if (lane < KNB) spair[w][lane] = make_float2(0.0f, __int_as_float(0));

  // load 16 keys: cols g*512 + lane*8 + e
  const uint4 u0 = *(const uint4*)(krow + lane * 8);
  const uint4 u1 = *(const uint4*)(krow + 512 + lane * 8);
  int k[16];
  {
    const unsigned uu[8] = {u0.x, u0.y, u0.z, u0.w, u1.x, u1.y, u1.z, u1.w};
#pragma unroll
    for (int q = 0; q < 8; ++q) {
      k[q * 2] = (int)(uu[q] & 0xffffu);
      k[q * 2 + 1] = (int)(uu[q] >> 16);
    }
  }
  // k[t] maps to col(t) = (t>>3)*512 + lane*8 + (t&7)

  float st[16];
#pragma unroll
  for (int t2 = 0; t2 < 16; ++t2) st[t2] = fmaf((float)k[t2] + 0.5f, KCELL, -8.0f);

  // radix-select 64th-largest key (16 bits)
  int cur = 0;
#pragma unroll 1
  for (int bit = 15; bit >= 0; --bit) {
    const int cand = cur | (1 << bit);
    int cnt = 0;
#pragma unroll
    for (int t2 = 0; t2 < 16; ++t2) cnt += (int)__popcll(__ballot(k[t2] >= cand));
    if (cnt >= KNB) cur = cand;
  }

  const int kHi = cur + 5;  // key >= kHi -> provably in top-64
  const int kLo = cur - 4;  // key <  kLo -> provably out

  const unsigned long long ltmask = (1ull << lane) - 1ull;
  unsigned hm = 0u, cm = 0u;
  int cpos[16];
  int nhi = 0, ncand = 0;
#pragma unroll
  for (int g = 0; g < 2; ++g) {
    bool hiv[8], cdv[8];
    unsigned long long mh[8], mc[8];
#pragma unroll
    for (int e = 0; e < 8; ++e) {
      const int t2 = g * 8 + e;
      hiv[e] = (k[t2] >= kHi);
      cdv[e] = (!hiv[e]) && (k[t2] >= kLo);
      mh[e] = __ballot(hiv[e]);
      mc[e] = __ballot(cdv[e]);
    }
    int below = 0, tot_h = 0, tot_c = 0;
#pragma unroll
    for (int e = 0; e < 8; ++e) {
      below += (int)__popcll(mc[e] & ltmask);
      tot_h += (int)__popcll(mh[e]);
      tot_c += (int)__popcll(mc[e]);
    }
    int own = 0;
#pragma unroll
    for (int e = 0; e < 8; ++e) {
      const int t2 = g * 8 + e;
      cpos[t2] = -1;
      if (hiv[e]) hm |= (1u << t2);
      if (cdv[e]) {
        cm |= (1u << t2);
        const int p = ncand + below + own;
        cpos[t2] = p;
        if (p < 32) cidxs[w][p] = g * 512 + lane * 8 + e;
        ++own;
      }
    }
    nhi += tot_h;
    ncand += tot_c;
  }
  const int need = KNB - nhi;  // >= 1; nhi+ncand >= 64

  unsigned selm;
  if (ncand == need) {
    selm = hm | cm;  // fast path (vast majority of rows)
  } else {
    const int nc = (ncand <= 32) ? ncand : 32;
    const int nd = (need <= nc) ? need : nc;
    const size_t qoff = (size_t)row * DD + lane * 4;
    const half4 q1v = *(const half4*)(Q1 + qoff);
    const half4 q2v = *(const half4*)(Q2 + qoff);
    float qf[4];
#pragma unroll
    for (int e = 0; e < 4; ++e) qf[e] = (float)q1v[e] + (float)q2v[e];
    const float* adjrow = adj + (size_t)m * NNODES;
#pragma unroll 2
    for (int t2 = 0; t2 < nc; ++t2) {
      const int j = cidxs[w][t2];
      const size_t koff = ((size_t)b * NNODES + j) * DD + lane * 4;
      const half4 k1v = *(const half4*)(K1 + koff);
      const half4 k2v = *(const half4*)(K2 + koff);
      float part = 0.0f;
#pragma unroll
      for (int e = 0; e < 4; ++e) part = fmaf(qf[e], (float)k1v[e] + (float)k2v[e], part);
#pragma unroll
      for (int off = 32; off > 0; off >>= 1) part += __shfl_xor(part, off);
      if (lane == 0) cex[w][t2] = part * INV65536 + adjrow[j];
    }
    if (lane < nc) {
      const float et = cex[w][lane];
      int rank = 0;
      for (int u = 0; u < nc; ++u) {
        const float eu = cex[w][u];
        rank += (eu > et || (eu == et && u < lane)) ? 1 : 0;
      }
      csel[w][lane] = (rank < nd) ? 1 : 0;
    }
    selm = hm;
#pragma unroll
    for (int t2 = 0; t2 < 16; ++t2) {
      if (((cm >> t2) & 1u) && cpos[t2] >= 0 && cpos[t2] < 32 && csel[w][cpos[t2]]) selm |= (1u << t2);
    }
  }

  // softmax over selected (rmax over all; the max element is hi|cand)
  float rmax = st[0];
#pragma unroll
  for (int t2 = 1; t2 < 16; ++t2) rmax = fmaxf(rmax, st[t2]);
#pragma unroll
  for (int off = 32; off > 0; off >>= 1) rmax = fmaxf(rmax, __shfl_xor(rmax, off));

  float p[16];
  float sum = 0.0f;
#pragma unroll
  for (int t2 = 0; t2 < 16; ++t2) {
    p[t2] = __expf(st[t2] - rmax);
    if ((selm >> t2) & 1u) sum += p[t2];
  }
#pragma unroll
  for (int off = 32; off > 0; off >>= 1) sum += __shfl_xor(sum, off);
  const float inv = 1.0f / sum;

  // attn write (overwrites full 4KB row incl. key half) + ordered compaction
  int run = 0;
#pragma unroll
  for (int g = 0; g < 2; ++g) {
    bool sel8[8];
    unsigned long long ms[8];
#pragma unroll
    for (int e = 0; e < 8; ++e) {
      sel8[e] = (selm >> (g * 8 + e)) & 1u;
      ms[e] = __ballot(sel8[e]);
    }
    int below = 0, tot = 0;
#pragma unroll
    for (int e = 0; e < 8; ++e) {
      below += (int)__popcll(ms[e] & ltmask);
      tot += (int)__popcll(ms[e]);
    }
    float ow[8];
    int own = 0;
#pragma unroll
    for (int e = 0; e < 8; ++e) {
      const int t2 = g * 8 + e;
      const float aw = sel8[e] ? p[t2] * inv : 0.0f;
      ow[e] = aw;
      if (sel8[e]) {
        const int pos = run + below + own;
        // store V16 row byte-offset: col * DD * 2
        if (pos < KNB)
          spair[w][pos] = make_float2(aw, __int_as_float((g * 512 + lane * 8 + e) * (DD * 2)));
        ++own;
      }
    }
    float* dst = Srow + g * 512 + lane * 8;
    *(float4*)(dst) = make_float4(ow[0], ow[1], ow[2], ow[3]);
    *(float4*)(dst + 4) = make_float4(ow[4], ow[5], ow[6], ow[7]);
    run += tot;
  }

  // messages: lane owns output dims [lane*4, lane*4+4)
  float4 acc = {0.0f, 0.0f, 0.0f, 0.0f};
  const char* Vbase = (const char*)(V16 + (size_t)b * NNODES * DD) + lane * 8;
#pragma unroll 4
  for (int t2 = 0; t2 < KNB; ++t2) {
    const float2 pr = spair[w][t2];
    const int off = __float_as_int(pr.y);
    const half4 vv = *(const half4*)(Vbase + off);
    acc.x = fmaf(pr.x, (float)vv[0], acc.x);
    acc.y = fmaf(pr.x, (float)vv[1], acc.y);
    acc.z = fmaf(pr.x, (float)vv[2], acc.z);
    acc.w = fmaf(pr.x, (float)vv[3], acc.w);
  }
  // M stored as single fp16(64*m) -- downstream w1 runs 2-product
  half4 m1;
  m1[0] = (_Float16)(acc.x * 64.0f);
  m1[1] = (_Float16)(acc.y * 64.0f);
  m1[2] = (_Float16)(acc.z * 64.0f);
  m1[3] = (_Float16)(acc.w * 64.0f);
  *(half4*)(M1 + (size_t)row * DD + lane * 4) = m1;
}

// =====================================================================
// LayerNorm + ReLU: H16 fp16 -> single fp16(64*y). Wave per row, no LDS.
// =====================================================================
__global__ __launch_bounds__(256) void ln_relu(const _Float16* __restrict__ H16,
                                               const float* __restrict__ g,
                                               const float* __restrict__ bta,
                                               _Float16* __restrict__ H1) {
  const int tid = threadIdx.x;
  const int row = blockIdx.x * 4 + (tid >> 6);
  const int lane = tid & 63;
  const half4 hv = *(const half4*)(H16 + (size_t)row * DD + lane * 4);
  float h[4];
#pragma unroll
  for (int j = 0; j < 4; ++j) h[j] = (float)hv[j];

  float s = h[0] + h[1] + h[2] + h[3];
#pragma unroll
  for (int off = 32; off > 0; off >>= 1) s += __shfl_xor(s, off);
  const float mu = s * (1.0f / 256.0f);

  float d[4], sq = 0.0f;
#pragma unroll
  for (int j = 0; j < 4; ++j) {
    d[j] = h[j] - mu;
    sq += d[j] * d[j];
  }
#pragma unroll
  for (int off = 32; off > 0; off >>= 1) sq += __shfl_xor(sq, off);
  const float rstd = 1.0f / sqrtf(sq * (1.0f / 256.0f) + 1e-5f);

  const float4 gv = *(const float4*)(g + lane * 4);
  const float4 bv = *(const float4*)(bta + lane * 4);
  const float gg[4] = {gv.x, gv.y, gv.z, gv.w};
  const float bb[4] = {bv.x, bv.y, bv.z, bv.w};
  half4 o;
#pragma unroll
  for (int j = 0; j < 4; ++j) {
    const float y = fmaxf(d[j] * rstd * gg[j] + bb[j], 0.0f);
    o[j] = (_Float16)(y * 64.0f);
  }
  *(half4*)(H1 + (size_t)row * DD + lane * 4) = o;
}

// =====================================================================
// Host launch
// =====================================================================
extern "C" void kernel_launch(void* const* d_in, const int* in_sizes, int n_in,
                              void* d_out, int out_size, void* d_ws, size_t ws_size,
                              hipStream_t stream) {
  (void)in_sizes; (void)n_in; (void)out_size; (void)ws_size;
  const float* x   = (const float*)d_in[0];
  const float* wq  = (const float*)d_in[1];
  const float* bq  = (const float*)d_in[2];
  const float* wk  = (const float*)d_in[3];
  const float* bk  = (const float*)d_in[4];
  const float* wv  = (const float*)d_in[5];
  const float* bv  = (const float*)d_in[6];
  const float* adj = (const float*)d_in[7];
  const float* w1  = (const float*)d_in[8];
  const float* b1  = (const float*)d_in[9];
  const float* lng = (const float*)d_in[10];
  const float* lnb = (const float*)d_in[11];
  const float* w2  = (const float*)d_in[12];
  const float* b2  = (const float*)d_in[13];

  const size_t BND = (size_t)MTOT * DD;  // 8,388,608
  float* outp  = (float*)d_out;          // [MTOT][256] (written by final w2 gemm)
  float* attnp = outp + BND;             // [MTOT][1024] (X splits -> keys+attn)

  // X1/X2 live in the attn scratch region (dead before scores writes keys)
  _Float16* X1 = (_Float16*)attnp;
  _Float16* X2 = X1 + BND;

  _Float16* Q1 = (_Float16*)d_ws;   // ~85 MB total ws use (proven available)
  _Float16* Q2 = Q1 + BND;
  _Float16* K1 = Q2 + BND;
  _Float16* K2 = K1 + BND;
  _Float16* WT = K2 + BND;          // [5][2][65536]
  _Float16* V16 = WT + 5 * 131072;  // fp16 V (16.78 MB)

  _Float16* M1 = Q1;          // reuse after topk (wave reads own Q row first)
  _Float16* H16 = (_Float16*)K1;  // reuse K1 region after topk (16 MB)
  _Float16* H1 = Q1;          // reuse after w1 consumed M1

  const dim3 blk(256);

  prep_wx<<<dim3(5376), blk, 0, stream>>>(x, X1, X2, wq, wk, wv, w1, w2, WT);
  gemm_qkv<<<dim3(1536), blk, 0, stream>>>(X1, X2, WT, bq, bk, bv, Q1, Q2, K1, K2, V16);
  gemm_split<2><<<dim3(2048), blk, 0, stream>>>(Q1, K1, K2, adj, nullptr, attnp, nullptr);
  topk_softmax_msg<<<dim3(MTOT / 4), blk, 0, stream>>>(attnp, V16, Q1, Q2, K1, K2, adj, M1);
  gemm_split<0><<<dim3(2, 256), blk, 0, stream>>>(M1, WT + 3 * 131072, WT + 3 * 131072 + 65536,
                                                  b1, nullptr, nullptr, H16);
  ln_relu<<<dim3(MTOT / 4), blk, 0, stream>>>(H16, lng, lnb, H1);
  gemm_split<1><<<dim3(2, 256), blk, 0, stream>>>(H1, WT + 4 * 131072, WT + 4 * 131072 + 65536,
                                                  b2, V16, outp, nullptr);
}

// Round 15
// 290.246 us; speedup vs baseline: 1.1164x; 1.0394x over previous
//
#include <hip/hip_runtime.h>
#include <cstdint>

#define NB 32
#define NNODES 1024
#define DD 256
#define KNB 64
#define MTOT (NB * NNODES)  // 32768

// Scaling: activations stored as split(64*a), weights as split(1024*w).
// acc = sum (64a)(1024w) = 65536 * a.w  -> epilogue * 1/65536.
// scores acc = (64q).(64k) = 4096 q.k -> q.k/16 = acc/65536 too.
#define INV65536 1.52587890625e-05f
// 16-bit key cell over [-8,8)
#define KCELL 2.44140625e-4f

typedef _Float16 half8 __attribute__((ext_vector_type(8)));
typedef _Float16 half4 __attribute__((ext_vector_type(4)));
typedef float f32x4 __attribute__((ext_vector_type(4)));

typedef __attribute__((address_space(3))) uint32_t lds_u32;
typedef __attribute__((address_space(1))) uint32_t glb_u32;

// 16B async global->LDS. LDS dest wave-uniform; HW adds lane*16.
__device__ __forceinline__ void gll16(const _Float16* g, _Float16* l) {
  __builtin_amdgcn_global_load_lds((const glb_u32*)g, (lds_u32*)l, 16, 0, 0);
}

__device__ __forceinline__ void split2(float v, _Float16& h, _Float16& l) {
  h = (_Float16)v;
  l = (_Float16)(v - (float)h);
}

// =====================================================================
// prep_wx: fused weight + activation pre-split (one launch).
// blocks [0,4096): x fp32 -> X1,X2 = split(64*x), 8 elems/thread.
// blocks [4096,5376): W[k][n] fp32 -> W_T[n][k] fp16x2, scaled by 1024.
// =====================================================================
__global__ __launch_bounds__(256) void prep_wx(const float* __restrict__ x,
                                               _Float16* __restrict__ X1,
                                               _Float16* __restrict__ X2,
                                               const float* __restrict__ wq,
                                               const float* __restrict__ wk,
                                               const float* __restrict__ wv,
                                               const float* __restrict__ w1,
                                               const float* __restrict__ w2,
                                               _Float16* __restrict__ WT) {
  if (blockIdx.x < 4096) {
    const size_t i = ((size_t)blockIdx.x * 256 + threadIdx.x) * 8;
    const float4 a = *(const float4*)(x + i);
    const float4 bb = *(const float4*)(x + i + 4);
    const float vals[8] = {a.x, a.y, a.z, a.w, bb.x, bb.y, bb.z, bb.w};
    half8 h, l;
#pragma unroll
    for (int e = 0; e < 8; ++e) {
      _Float16 hh, ll;
      split2(vals[e] * 64.0f, hh, ll);
      h[e] = hh;
      l[e] = ll;
    }
    *(half8*)(X1 + i) = h;
    *(half8*)(X2 + i) = l;
  } else {
    const int idx = (blockIdx.x - 4096) * 256 + threadIdx.x;  // < 5*65536
    const int wsel = idx >> 16;
    const int rem = idx & 65535;
    const int k = rem >> 8, n = rem & 255;
    const float* src = (wsel == 0) ? wq : (wsel == 1) ? wk : (wsel == 2) ? wv : (wsel == 3) ? w1 : w2;
    const float v = src[rem] * 1024.0f;
    _Float16 h1, h2;
    split2(v, h1, h2);
    WT[(size_t)wsel * 131072 + n * 256 + k] = h1;
    WT[(size_t)wsel * 131072 + 65536 + n * 256 + k] = h2;
  }
}

// LDS tile layout: [128 rows][8 chunks of 8 halfs], chunk XOR-swizzled by (row&7)
#define SWZ_OFF(r, cc) ((r) * 64 + (((cc) ^ ((r)&7)) << 3))

// =====================================================================
// gemm_qkv: A=X1/X2 pre-split, B=WT, all via global_load_lds.
// Q,K: 3 products (selection-critical). V: 1 product -> fp16 only.
// Grid 1D 1536, XCD-swizzled: 6 sibling blocks (same m-rows) per XCD.
// =====================================================================
__global__ __launch_bounds__(256) void gemm_qkv(const _Float16* __restrict__ X1,
                                                const _Float16* __restrict__ X2,
                                                const _Float16* __restrict__ WT,
                                                const float* __restrict__ bq,
                                                const float* __restrict__ bk,
                                                const float* __restrict__ bv,
                                                _Float16* __restrict__ Q1, _Float16* __restrict__ Q2,
                                                _Float16* __restrict__ K1, _Float16* __restrict__ K2,
                                                _Float16* __restrict__ V16) {
  __shared__ _Float16 sm[4 * 8192];
  _Float16* sA1 = sm;
  _Float16* sA2 = sm + 8192;
  _Float16* sB1 = sm + 16384;
  _Float16* sB2 = sm + 24576;

  const int tid = threadIdx.x;
  const int lane = tid & 63, w = tid >> 6;
  const int r16 = lane & 15, kg = lane >> 4;
  const int rsub = lane >> 3, csub = lane & 7;
  const int wm = (w >> 1) * 64, wn = (w & 1) * 64;

  // XCD swizzle: id%8 = XCD; 6 siblings (j=0..5) of each m-tile share id%8
  const int id = blockIdx.x;
  const int c8 = id & 7, t = id >> 3;   // t in 0..191
  const int gy = (t / 6) * 8 + c8;      // m-tile 0..255
  const int j6 = t % 6;
  const int wsel = j6 >> 1;
  const int n0 = (j6 & 1) * 128;
  const int m0 = gy * 128;
  const bool full = (wsel != 2);  // Q,K need 3 products; V needs 1

  const _Float16* pB1 = WT + (size_t)wsel * 131072;
  const _Float16* pB2 = pB1 + 65536;

  f32x4 acc[4][4];
#pragma unroll
  for (int i = 0; i < 4; ++i)
#pragma unroll
    for (int j = 0; j < 4; ++j) acc[i][j] = f32x4{0.f, 0.f, 0.f, 0.f};

  for (int k0 = 0; k0 < DD; k0 += 64) {
    __syncthreads();
#pragma unroll
    for (int it = 0; it < 4; ++it) {
      const int r = (w << 5) + (it << 3) + rsub;
      const int swz = ((csub ^ (r & 7)) << 3);
      const int ldso = (w << 11) + (it << 9);
      gll16(X1 + (size_t)(m0 + r) * DD + k0 + swz, sA1 + ldso);
      gll16(pB1 + (size_t)(n0 + r) * DD + k0 + swz, sB1 + ldso);
      if (full) {
        gll16(X2 + (size_t)(m0 + r) * DD + k0 + swz, sA2 + ldso);
        gll16(pB2 + (size_t)(n0 + r) * DD + k0 + swz, sB2 + ldso);
      }
    }
    __syncthreads();

#pragma unroll
    for (int s = 0; s < 2; ++s) {
      half8 aA[4], aB[4], bA[4], bB[4];
#pragma unroll
      for (int mi = 0; mi < 4; ++mi) {
        const int off = SWZ_OFF(wm + mi * 16 + r16, s * 4 + kg);
        aA[mi] = *(const half8*)(sA1 + off);
      }
#pragma unroll
      for (int nj = 0; nj < 4; ++nj) {
        const int off = SWZ_OFF(wn + nj * 16 + r16, s * 4 + kg);
        bA[nj] = *(const half8*)(sB1 + off);
      }
      if (full) {
#pragma unroll
        for (int mi = 0; mi < 4; ++mi) {
          const int off = SWZ_OFF(wm + mi * 16 + r16, s * 4 + kg);
          aB[mi] = *(const half8*)(sA2 + off);
        }
#pragma unroll
        for (int nj = 0; nj < 4; ++nj) {
          const int off = SWZ_OFF(wn + nj * 16 + r16, s * 4 + kg);
          bB[nj] = *(const half8*)(sB2 + off);
        }
      }
#pragma unroll
      for (int mi = 0; mi < 4; ++mi)
#pragma unroll
        for (int nj = 0; nj < 4; ++nj) {
          acc[mi][nj] = __builtin_amdgcn_mfma_f32_16x16x32_f16(aA[mi], bA[nj], acc[mi][nj], 0, 0, 0);
          if (full) {
            acc[mi][nj] = __builtin_amdgcn_mfma_f32_16x16x32_f16(aA[mi], bB[nj], acc[mi][nj], 0, 0, 0);
            acc[mi][nj] = __builtin_amdgcn_mfma_f32_16x16x32_f16(aB[mi], bA[nj], acc[mi][nj], 0, 0, 0);
          }
        }
    }
  }

  const float* bsel = (wsel == 0) ? bq : (wsel == 1) ? bk : bv;
  _Float16* P1 = (wsel == 0) ? Q1 : K1;
  _Float16* P2 = (wsel == 0) ? Q2 : K2;
#pragma unroll
  for (int mi = 0; mi < 4; ++mi)
#pragma unroll
    for (int nj = 0; nj < 4; ++nj) {
      const int col = n0 + wn + nj * 16 + r16;
#pragma unroll
      for (int j = 0; j < 4; ++j) {
        const int rr = m0 + wm + mi * 16 + kg * 4 + j;
        if (wsel == 2) {
          V16[(size_t)rr * DD + col] = (_Float16)(acc[mi][nj][j] * INV65536 + bsel[col]);
        } else {
          // store 64*Q = acc/1024 + 64*bias
          const float qv = acc[mi][nj][j] * (1.0f / 1024.0f) + 64.0f * bsel[col];
          _Float16 h1, h2;
          split2(qv, h1, h2);
          P1[(size_t)rr * DD + col] = h1;
          P2[(size_t)rr * DD + col] = h2;
        }
      }
    }
}

// =====================================================================
// gemm_split<EPI>: A single-split fp16, B pre-split fp16x2 (NT).
// EPI 0: H16 = fp16(acc/65536 + bias)      (w1 -> H16), 2 products
// EPI 1: C = acc/65536 + bias + resid16    (w2 -> out), 2 products
// EPI 2: scores -> u16 keys, 1 PRODUCT (Q1.K1 only; both dropped terms
//        sigma ~0.57 cells, covered by topk's widened +-6/+7 band with
//        exact fp32 recompute). 2 streams staged, 32KB LDS.
//        Grid 1D 2048 XCD-swizzled (batch -> one XCD, K_b L2-resident).
// =====================================================================
template <int EPI>
__global__ __launch_bounds__(256) void gemm_split(const _Float16* __restrict__ A1,
                                                  const _Float16* __restrict__ B1g,
                                                  const _Float16* __restrict__ B2g,
                                                  const float* __restrict__ bias,
                                                  const _Float16* __restrict__ resid16,
                                                  float* __restrict__ C,
                                                  _Float16* __restrict__ C16) {
  __shared__ _Float16 sm[(EPI == 2 ? 2 : 3) * 8192];
  _Float16* sA1 = sm;
  _Float16* sB1 = sm + 8192;
  _Float16* sB2 = sm + 16384;  // unused for EPI==2

  const int tid = threadIdx.x;
  const int lane = tid & 63, w = tid >> 6;
  const int r16 = lane & 15, kg = lane >> 4;
  const int rsub = lane >> 3, csub = lane & 7;
  const int wm = (w >> 1) * 64, wn = (w & 1) * 64;

  int n0, m0;
  if (EPI == 2) {
    // XCD swizzle: batch Bb's 64 blocks share id%8 = one XCD
    const int id = blockIdx.x;
    const int c8 = id & 7, t = id >> 3;   // t in 0..255
    const int Bb = ((t >> 6) << 3) + c8;  // batch 0..31
    const int r = (t >> 3) & 7;           // m sub-tile
    const int bx = t & 7;                 // n tile
    n0 = bx * 128;
    m0 = (Bb * 8 + r) * 128;
  } else {
    n0 = blockIdx.x * 128;
    m0 = blockIdx.y * 128;
  }

  const _Float16* pB1 = B1g;
  const _Float16* pB2 = B2g;
  if (EPI == 2) {
    const size_t boff = (size_t)(m0 >> 10) * NNODES * DD;
    pB1 += boff;
  }

  f32x4 acc[4][4];
#pragma unroll
  for (int i = 0; i < 4; ++i)
#pragma unroll
    for (int j = 0; j < 4; ++j) acc[i][j] = f32x4{0.f, 0.f, 0.f, 0.f};

  for (int k0 = 0; k0 < DD; k0 += 64) {
    __syncthreads();
#pragma unroll
    for (int it = 0; it < 4; ++it) {
      const int r = (w << 5) + (it << 3) + rsub;
      const int swz = ((csub ^ (r & 7)) << 3);
      const int ldso = (w << 11) + (it << 9);
      gll16(A1 + (size_t)(m0 + r) * DD + k0 + swz, sA1 + ldso);
      gll16(pB1 + (size_t)(n0 + r) * DD + k0 + swz, sB1 + ldso);
      if (EPI != 2) gll16(pB2 + (size_t)(n0 + r) * DD + k0 + swz, sB2 + ldso);
    }
    __syncthreads();

#pragma unroll
    for (int s = 0; s < 2; ++s) {
      half8 aA[4], bA[4], bB[4];
#pragma unroll
      for (int mi = 0; mi < 4; ++mi) {
        const int off = SWZ_OFF(wm + mi * 16 + r16, s * 4 + kg);
        aA[mi] = *(const half8*)(sA1 + off);
      }
#pragma unroll
      for (int nj = 0; nj < 4; ++nj) {
        const int off = SWZ_OFF(wn + nj * 16 + r16, s * 4 + kg);
        bA[nj] = *(const half8*)(sB1 + off);
        if (EPI != 2) bB[nj] = *(const half8*)(sB2 + off);
      }
#pragma unroll
      for (int mi = 0; mi < 4; ++mi)
#pragma unroll
        for (int nj = 0; nj < 4; ++nj) {
          acc[mi][nj] = __builtin_amdgcn_mfma_f32_16x16x32_f16(aA[mi], bA[nj], acc[mi][nj], 0, 0, 0);
          if (EPI != 2)
            acc[mi][nj] = __builtin_amdgcn_mfma_f32_16x16x32_f16(aA[mi], bB[nj], acc[mi][nj], 0, 0, 0);
        }
    }
  }

#pragma unroll
  for (int mi = 0; mi < 4; ++mi)
#pragma unroll
    for (int nj = 0; nj < 4; ++nj) {
      const int col = n0 + wn + nj * 16 + r16;
#pragma unroll
      for (int j = 0; j < 4; ++j) {
        const int rr = m0 + wm + mi * 16 + kg * 4 + j;
        const float v = acc[mi][nj][j] * INV65536;
        if (EPI == 2) {
          const float sv = v + bias[(size_t)(rr & (NNODES - 1)) * NNODES + col];
          const float f = fminf(fmaxf((sv + 8.0f) * 4096.0f, 0.0f), 65535.0f);
          uint16_t* kbase = (uint16_t*)((char*)C + (size_t)rr * 4096 + 2048);
          kbase[col] = (uint16_t)(unsigned)f;
        } else if (EPI == 0) {
          C16[(size_t)rr * DD + col] = (_Float16)(v + bias[col]);
        } else {
          C[(size_t)rr * DD + col] = v + bias[col] + (float)resid16[(size_t)rr * DD + col];
        }
      }
    }
}

// =====================================================================
// Top-64 from u16 keys + masked softmax + sparse messages. One wave/row.
// r10-proven structure (VGPR 32, occ 62%). Band widened for 1-product
// scores (sigma ~0.57 cells): hi key>=cur+7 (provably in), out key<cur-6
// (provably out) -- 5-cell score margin ~ 8.8 sigma (stronger than the
// proven 2-product/+-4 config). Candidates: exact fp32 recompute from
// split Q,K; jax tie semantics (score desc, index asc).
// =====================================================================
__global__ __launch_bounds__(256, 4) void topk_softmax_msg(float* __restrict__ S,
                                                           const _Float16* __restrict__ V16,
                                                           const _Float16* __restrict__ Q1,
                                                           const _Float16* __restrict__ Q2,
                                                           const _Float16* __restrict__ K1,
                                                           const _Float16* __restrict__ K2,
                                                           const float* __restrict__ adj,
                                                           _Float16* __restrict__ M1) {
  const int tid = threadIdx.x;
  const int w = tid >> 6, lane = tid & 63;
  // XCD swizzle: batch = (t>>8)*8 + id%8 -> whole batch on one XCD
  const int id = blockIdx.x;            // 0..8191
  const int xcd = id & 7, t = id >> 3;  // t 0..1023
  const int b = (t >> 8) * 8 + xcd;     // batch 0..31
  const int row = b * NNODES + (t & 255) * 4 + w;
  const int m = row & (NNODES - 1);
  float* Srow = S + (size_t)row * NNODES;
  const uint16_t* krow = (const uint16_t*)((const char*)S + (size_t)row * 4096 + 2048);

  __shared__ float2 spair[4][KNB];  // (wgt, V16 row byte-offset bits)
  __shared__ int cidxs[4][32];
  __shared__ float cex[4][32];
  __shared__ int csel[4][32];

  if (lane < KNB) spair[w][lane] = make_float2(0.0f, __int_as_float(0));

  // load 16 keys: cols g*512 + lane*8 + e
  const uint4 u0 = *(const uint4*)(krow + lane * 8);
  const uint4 u1 = *(const uint4*)(krow + 512 + lane * 8);
  int k[16];
  {
    const unsigned uu[8] = {u0.x, u0.y, u0.z, u0.w, u1.x, u1.y, u1.z, u1.w};
#pragma unroll
    for (int q = 0; q < 8; ++q) {
      k[q * 2] = (int)(uu[q] & 0xffffu);
      k[q * 2 + 1] = (int)(uu[q] >> 16);
    }
  }
  // k[t] maps to col(t) = (t>>3)*512 + lane*8 + (t&7)

  float st[16];
#pragma unroll
  for (int t2 = 0; t2 < 16; ++t2) st[t2] = fmaf((float)k[t2] + 0.5f, KCELL, -8.0f);

  // radix-select 64th-largest key (16 bits)
  int cur = 0;
#pragma unroll 1
  for (int bit = 15; bit >= 0; --bit) {
    const int cand = cur | (1 << bit);
    int cnt = 0;
#pragma unroll
    for (int t2 = 0; t2 < 16; ++t2) cnt += (int)__popcll(__ballot(k[t2] >= cand));
    if (cnt >= KNB) cur = cand;
  }

  const int kHi = cur + 7;  // key >= kHi -> provably in top-64
  const int kLo = cur - 6;  // key <  kLo -> provably out

  const unsigned long long ltmask = (1ull << lane) - 1ull;
  unsigned hm = 0u, cm = 0u;
  int cpos[16];
  int nhi = 0, ncand = 0;
#pragma unroll
  for (int g = 0; g < 2; ++g) {
    bool hiv[8], cdv[8];
    unsigned long long mh[8], mc[8];
#pragma unroll
    for (int e = 0; e < 8; ++e) {
      const int t2 = g * 8 + e;
      hiv[e] = (k[t2] >= kHi);
      cdv[e] = (!hiv[e]) && (k[t2] >= kLo);
      mh[e] = __ballot(hiv[e]);
      mc[e] = __ballot(cdv[e]);
    }
    int below = 0, tot_h = 0, tot_c = 0;
#pragma unroll
    for (int e = 0; e < 8; ++e) {
      below += (int)__popcll(mc[e] & ltmask);
      tot_h += (int)__popcll(mh[e]);
      tot_c += (int)__popcll(mc[e]);
    }
    int own = 0;
#pragma unroll
    for (int e = 0; e < 8; ++e) {
      const int t2 = g * 8 + e;
      cpos[t2] = -1;
      if (hiv[e]) hm |= (1u << t2);
      if (cdv[e]) {
        cm |= (1u << t2);
        const int p = ncand + below + own;
        cpos[t2] = p;
        if (p < 32) cidxs[w][p] = g * 512 + lane * 8 + e;
        ++own;
      }
    }
    nhi += tot_h;
    ncand += tot_c;
  }
  const int need = KNB - nhi;  // >= 1; nhi+ncand >= 64

  unsigned selm;
  if (ncand == need) {
    selm = hm | cm;  // fast path (most rows)
  } else {
    const int nc = (ncand <= 32) ? ncand : 32;
    const int nd = (need <= nc) ? need : nc;
    const size_t qoff = (size_t)row * DD + lane * 4;
    const half4 q1v = *(const half4*)(Q1 + qoff);
    const half4 q2v = *(const half4*)(Q2 + qoff);
    float qf[4];
#pragma unroll
    for (int e = 0; e < 4; ++e) qf[e] = (float)q1v[e] + (float)q2v[e];
    const float* adjrow = adj + (size_t)m * NNODES;
#pragma unroll 2
    for (int t2 = 0; t2 < nc; ++t2) {
      const int j = cidxs[w][t2];
      const size_t koff = ((size_t)b * NNODES + j) * DD + lane * 4;
      const half4 k1v = *(const half4*)(K1 + koff);
      const half4 k2v = *(const half4*)(K2 + koff);
      float part = 0.0f;
#pragma unroll
      for (int e = 0; e < 4; ++e) part = fmaf(qf[e], (float)k1v[e] + (float)k2v[e], part);
#pragma unroll
      for (int off = 32; off > 0; off >>= 1) part += __shfl_xor(part, off);
      if (lane == 0) cex[w][t2] = part * INV65536 + adjrow[j];
    }
    if (lane < nc) {
      const float et = cex[w][lane];
      int rank = 0;
      for (int u = 0; u < nc; ++u) {
        const float eu = cex[w][u];
        rank += (eu > et || (eu == et && u < lane)) ? 1 : 0;
      }
      csel[w][lane] = (rank < nd) ? 1 : 0;
    }
    selm = hm;
#pragma unroll
    for (int t2 = 0; t2 < 16; ++t2) {
      if (((cm >> t2) & 1u) && cpos[t2] >= 0 && cpos[t2] < 32 && csel[w][cpos[t2]]) selm |= (1u << t2);
    }
  }

  // softmax over selected (rmax over all; the max element is hi|cand)
  float rmax = st[0];
#pragma unroll
  for (int t2 = 1; t2 < 16; ++t2) rmax = fmaxf(rmax, st[t2]);
#pragma unroll
  for (int off = 32; off > 0; off >>= 1) rmax = fmaxf(rmax, __shfl_xor(rmax, off));

  float p[16];
  float sum = 0.0f;
#pragma unroll
  for (int t2 = 0; t2 < 16; ++t2) {
    p[t2] = __expf(st[t2] - rmax);
    if ((selm >> t2) & 1u) sum += p[t2];
  }
#pragma unroll
  for (int off = 32; off > 0; off >>= 1) sum += __shfl_xor(sum, off);
  const float inv = 1.0f / sum;

  // attn write (overwrites full 4KB row incl. key half) + ordered compaction
  int run = 0;
#pragma unroll
  for (int g = 0; g < 2; ++g) {
    bool sel8[8];
    unsigned long long ms[8];
#pragma unroll
    for (int e = 0; e < 8; ++e) {
      sel8[e] = (selm >> (g * 8 + e)) & 1u;
      ms[e] = __ballot(sel8[e]);
    }
    int below = 0, tot = 0;
#pragma unroll
    for (int e = 0; e < 8; ++e) {
      below += (int)__popcll(ms[e] & ltmask);
      tot += (int)__popcll(ms[e]);
    }
    float ow[8];
    int own = 0;
#pragma unroll
    for (int e = 0; e < 8; ++e) {
      const int t2 = g * 8 + e;
      const float aw = sel8[e] ? p[t2] * inv : 0.0f;
      ow[e] = aw;
      if (sel8[e]) {
        const int pos = run + below + own;
        // store V16 row byte-offset: col * DD * 2
        if (pos < KNB)
          spair[w][pos] = make_float2(aw, __int_as_float((g * 512 + lane * 8 + e) * (DD * 2)));
        ++own;
      }
    }
    float* dst = Srow + g * 512 + lane * 8;
    *(float4*)(dst) = make_float4(ow[0], ow[1], ow[2], ow[3]);
    *(float4*)(dst + 4) = make_float4(ow[4], ow[5], ow[6], ow[7]);
    run += tot;
  }

  // messages: lane owns output dims [lane*4, lane*4+4)
  float4 acc = {0.0f, 0.0f, 0.0f, 0.0f};
  const char* Vbase = (const char*)(V16 + (size_t)b * NNODES * DD) + lane * 8;
#pragma unroll 4
  for (int t2 = 0; t2 < KNB; ++t2) {
    const float2 pr = spair[w][t2];
    const int off = __float_as_int(pr.y);
    const half4 vv = *(const half4*)(Vbase + off);
    acc.x = fmaf(pr.x, (float)vv[0], acc.x);
    acc.y = fmaf(pr.x, (float)vv[1], acc.y);
    acc.z = fmaf(pr.x, (float)vv[2], acc.z);
    acc.w = fmaf(pr.x, (float)vv[3], acc.w);
  }
  // M stored as single fp16(64*m) -- downstream w1 runs 2-product
  half4 m1;
  m1[0] = (_Float16)(acc.x * 64.0f);
  m1[1] = (_Float16)(acc.y * 64.0f);
  m1[2] = (_Float16)(acc.z * 64.0f);
  m1[3] = (_Float16)(acc.w * 64.0f);
  *(half4*)(M1 + (size_t)row * DD + lane * 4) = m1;
}

// =====================================================================
// LayerNorm + ReLU: H16 fp16 -> single fp16(64*y). Wave per row, no LDS.
// =====================================================================
__global__ __launch_bounds__(256) void ln_relu(const _Float16* __restrict__ H16,
                                               const float* __restrict__ g,
                                               const float* __restrict__ bta,
                                               _Float16* __restrict__ H1) {
  const int tid = threadIdx.x;
  const int row = blockIdx.x * 4 + (tid >> 6);
  const int lane = tid & 63;
  const half4 hv = *(const half4*)(H16 + (size_t)row * DD + lane * 4);
  float h[4];
#pragma unroll
  for (int j = 0; j < 4; ++j) h[j] = (float)hv[j];

  float s = h[0] + h[1] + h[2] + h[3];
#pragma unroll
  for (int off = 32; off > 0; off >>= 1) s += __shfl_xor(s, off);
  const float mu = s * (1.0f / 256.0f);

  float d[4], sq = 0.0f;
#pragma unroll
  for (int j = 0; j < 4; ++j) {
    d[j] = h[j] - mu;
    sq += d[j] * d[j];
  }
#pragma unroll
  for (int off = 32; off > 0; off >>= 1) sq += __shfl_xor(sq, off);
  const float rstd = 1.0f / sqrtf(sq * (1.0f / 256.0f) + 1e-5f);

  const float4 gv = *(const float4*)(g + lane * 4);
  const float4 bv = *(const float4*)(bta + lane * 4);
  const float gg[4] = {gv.x, gv.y, gv.z, gv.w};
  const float bb[4] = {bv.x, bv.y, bv.z, bv.w};
  half4 o;
#pragma unroll
  for (int j = 0; j < 4; ++j) {
    const float y = fmaxf(d[j] * rstd * gg[j] + bb[j], 0.0f);
    o[j] = (_Float16)(y * 64.0f);
  }
  *(half4*)(H1 + (size_t)row * DD + lane * 4) = o;
}

// =====================================================================
// Host launch
// =====================================================================
extern "C" void kernel_launch(void* const* d_in, const int* in_sizes, int n_in,
                              void* d_out, int out_size, void* d_ws, size_t ws_size,
                              hipStream_t stream) {
  (void)in_sizes; (void)n_in; (void)out_size; (void)ws_size;
  const float* x   = (const float*)d_in[0];
  const float* wq  = (const float*)d_in[1];
  const float* bq  = (const float*)d_in[2];
  const float* wk  = (const float*)d_in[3];
  const float* bk  = (const float*)d_in[4];
  const float* wv  = (const float*)d_in[5];
  const float* bv  = (const float*)d_in[6];
  const float* adj = (const float*)d_in[7];
  const float* w1  = (const float*)d_in[8];
  const float* b1  = (const float*)d_in[9];
  const float* lng = (const float*)d_in[10];
  const float* lnb = (const float*)d_in[11];
  const float* w2  = (const float*)d_in[12];
  const float* b2  = (const float*)d_in[13];

  const size_t BND = (size_t)MTOT * DD;  // 8,388,608
  float* outp  = (float*)d_out;          // [MTOT][256] (written by final w2 gemm)
  float* attnp = outp + BND;             // [MTOT][1024] (X splits -> keys+attn)

  // X1/X2 live in the attn scratch region (dead before scores writes keys)
  _Float16* X1 = (_Float16*)attnp;
  _Float16* X2 = X1 + BND;

  _Float16* Q1 = (_Float16*)d_ws;   // ~85 MB total ws use (proven available)
  _Float16* Q2 = Q1 + BND;
  _Float16* K1 = Q2 + BND;
  _Float16* K2 = K1 + BND;
  _Float16* WT = K2 + BND;          // [5][2][65536]
  _Float16* V16 = WT + 5 * 131072;  // fp16 V (16.78 MB)

  _Float16* M1 = Q1;          // reuse after topk (wave reads own Q row first)
  _Float16* H16 = (_Float16*)K1;  // reuse K1 region after topk (16 MB)
  _Float16* H1 = Q1;          // reuse after w1 consumed M1

  const dim3 blk(256);

  prep_wx<<<dim3(5376), blk, 0, stream>>>(x, X1, X2, wq, wk, wv, w1, w2, WT);
  gemm_qkv<<<dim3(1536), blk, 0, stream>>>(X1, X2, WT, bq, bk, bv, Q1, Q2, K1, K2, V16);
  gemm_split<2><<<dim3(2048), blk, 0, stream>>>(Q1, K1, K2, adj, nullptr, attnp, nullptr);
  topk_softmax_msg<<<dim3(MTOT / 4), blk, 0, stream>>>(attnp, V16, Q1, Q2, K1, K2, adj, M1);
  gemm_split<0><<<dim3(2, 256), blk, 0, stream>>>(M1, WT + 3 * 131072, WT + 3 * 131072 + 65536,
                                                  b1, nullptr, nullptr, H16);
  ln_relu<<<dim3(MTOT / 4), blk, 0, stream>>>(H16, lng, lnb, H1);
  gemm_split<1><<<dim3(2, 256), blk, 0, stream>>>(H1, WT + 4 * 131072, WT + 4 * 131072 + 65536,
                                                  b2, V16, outp, nullptr);
}

// Round 16
// 279.601 us; speedup vs baseline: 1.1589x; 1.0381x over previous
//
#include <hip/hip_runtime.h>
#include <cstdint>

#define NB 32
#define NNODES 1024
#define DD 256
#define KNB 64
#define MTOT (NB * NNODES)  // 32768

// Scaling: activations stored as split(64*a), weights as split(1024*w).
// acc = sum (64a)(1024w) = 65536 * a.w  -> epilogue * 1/65536.
#define INV65536 1.52587890625e-05f
// 16-bit key cell over [-8,8)
#define KCELL 2.44140625e-4f

typedef _Float16 half8 __attribute__((ext_vector_type(8)));
typedef _Float16 half4 __attribute__((ext_vector_type(4)));
typedef float f32x4 __attribute__((ext_vector_type(4)));

typedef __attribute__((address_space(3))) uint32_t lds_u32;
typedef __attribute__((address_space(1))) uint32_t glb_u32;

// 16B async global->LDS. LDS dest wave-uniform; HW adds lane*16.
__device__ __forceinline__ void gll16(const _Float16* g, _Float16* l) {
  __builtin_amdgcn_global_load_lds((const glb_u32*)g, (lds_u32*)l, 16, 0, 0);
}

__device__ __forceinline__ void split2(float v, _Float16& h, _Float16& l) {
  h = (_Float16)v;
  l = (_Float16)(v - (float)h);
}

// =====================================================================
// prep_wx: fused weight + activation pre-split (one launch).
// blocks [0,4096): x fp32 -> X1,X2 = split(64*x), 8 elems/thread.
// blocks [4096,5376): W[k][n] fp32 -> W_T[n][k] fp16x2, scaled by 1024.
// =====================================================================
__global__ __launch_bounds__(256) void prep_wx(const float* __restrict__ x,
                                               _Float16* __restrict__ X1,
                                               _Float16* __restrict__ X2,
                                               const float* __restrict__ wq,
                                               const float* __restrict__ wk,
                                               const float* __restrict__ wv,
                                               const float* __restrict__ w1,
                                               const float* __restrict__ w2,
                                               _Float16* __restrict__ WT) {
  if (blockIdx.x < 4096) {
    const size_t i = ((size_t)blockIdx.x * 256 + threadIdx.x) * 8;
    const float4 a = *(const float4*)(x + i);
    const float4 bb = *(const float4*)(x + i + 4);
    const float vals[8] = {a.x, a.y, a.z, a.w, bb.x, bb.y, bb.z, bb.w};
    half8 h, l;
#pragma unroll
    for (int e = 0; e < 8; ++e) {
      _Float16 hh, ll;
      split2(vals[e] * 64.0f, hh, ll);
      h[e] = hh;
      l[e] = ll;
    }
    *(half8*)(X1 + i) = h;
    *(half8*)(X2 + i) = l;
  } else {
    const int idx = (blockIdx.x - 4096) * 256 + threadIdx.x;  // < 5*65536
    const int wsel = idx >> 16;
    const int rem = idx & 65535;
    const int k = rem >> 8, n = rem & 255;
    const float* src = (wsel == 0) ? wq : (wsel == 1) ? wk : (wsel == 2) ? wv : (wsel == 3) ? w1 : w2;
    const float v = src[rem] * 1024.0f;
    _Float16 h1, h2;
    split2(v, h1, h2);
    WT[(size_t)wsel * 131072 + n * 256 + k] = h1;
    WT[(size_t)wsel * 131072 + 65536 + n * 256 + k] = h2;
  }
}

// LDS tile layout: [rows][8 chunks of 8 halfs], chunk XOR-swizzled by (row&7)
#define SWZ_OFF(r, cc) ((r) * 64 + (((cc) ^ ((r)&7)) << 3))

// =====================================================================
// gemm_qkv: A=X1/X2 pre-split, B=WT, all via global_load_lds.
// Q,K: 3 products (selection-critical). V: 1 product -> fp16 only.
// Grid 1D 1536, XCD-swizzled: 6 sibling blocks (same m-rows) per XCD.
// =====================================================================
__global__ __launch_bounds__(256) void gemm_qkv(const _Float16* __restrict__ X1,
                                                const _Float16* __restrict__ X2,
                                                const _Float16* __restrict__ WT,
                                                const float* __restrict__ bq,
                                                const float* __restrict__ bk,
                                                const float* __restrict__ bv,
                                                _Float16* __restrict__ Q1, _Float16* __restrict__ Q2,
                                                _Float16* __restrict__ K1, _Float16* __restrict__ K2,
                                                _Float16* __restrict__ V16) {
  __shared__ _Float16 sm[4 * 8192];
  _Float16* sA1 = sm;
  _Float16* sA2 = sm + 8192;
  _Float16* sB1 = sm + 16384;
  _Float16* sB2 = sm + 24576;

  const int tid = threadIdx.x;
  const int lane = tid & 63, w = tid >> 6;
  const int r16 = lane & 15, kg = lane >> 4;
  const int rsub = lane >> 3, csub = lane & 7;
  const int wm = (w >> 1) * 64, wn = (w & 1) * 64;

  // XCD swizzle: id%8 = XCD; 6 siblings (j=0..5) of each m-tile share id%8
  const int id = blockIdx.x;
  const int c8 = id & 7, t = id >> 3;   // t in 0..191
  const int gy = (t / 6) * 8 + c8;      // m-tile 0..255
  const int j6 = t % 6;
  const int wsel = j6 >> 1;
  const int n0 = (j6 & 1) * 128;
  const int m0 = gy * 128;
  const bool full = (wsel != 2);  // Q,K need 3 products; V needs 1

  const _Float16* pB1 = WT + (size_t)wsel * 131072;
  const _Float16* pB2 = pB1 + 65536;

  f32x4 acc[4][4];
#pragma unroll
  for (int i = 0; i < 4; ++i)
#pragma unroll
    for (int j = 0; j < 4; ++j) acc[i][j] = f32x4{0.f, 0.f, 0.f, 0.f};

  for (int k0 = 0; k0 < DD; k0 += 64) {
    __syncthreads();
#pragma unroll
    for (int it = 0; it < 4; ++it) {
      const int r = (w << 5) + (it << 3) + rsub;
      const int swz = ((csub ^ (r & 7)) << 3);
      const int ldso = (w << 11) + (it << 9);
      gll16(X1 + (size_t)(m0 + r) * DD + k0 + swz, sA1 + ldso);
      gll16(pB1 + (size_t)(n0 + r) * DD + k0 + swz, sB1 + ldso);
      if (full) {
        gll16(X2 + (size_t)(m0 + r) * DD + k0 + swz, sA2 + ldso);
        gll16(pB2 + (size_t)(n0 + r) * DD + k0 + swz, sB2 + ldso);
      }
    }
    __syncthreads();

#pragma unroll
    for (int s = 0; s < 2; ++s) {
      half8 aA[4], aB[4], bA[4], bB[4];
#pragma unroll
      for (int mi = 0; mi < 4; ++mi) {
        const int off = SWZ_OFF(wm + mi * 16 + r16, s * 4 + kg);
        aA[mi] = *(const half8*)(sA1 + off);
      }
#pragma unroll
      for (int nj = 0; nj < 4; ++nj) {
        const int off = SWZ_OFF(wn + nj * 16 + r16, s * 4 + kg);
        bA[nj] = *(const half8*)(sB1 + off);
      }
      if (full) {
#pragma unroll
        for (int mi = 0; mi < 4; ++mi) {
          const int off = SWZ_OFF(wm + mi * 16 + r16, s * 4 + kg);
          aB[mi] = *(const half8*)(sA2 + off);
        }
#pragma unroll
        for (int nj = 0; nj < 4; ++nj) {
          const int off = SWZ_OFF(wn + nj * 16 + r16, s * 4 + kg);
          bB[nj] = *(const half8*)(sB2 + off);
        }
      }
#pragma unroll
      for (int mi = 0; mi < 4; ++mi)
#pragma unroll
        for (int nj = 0; nj < 4; ++nj) {
          acc[mi][nj] = __builtin_amdgcn_mfma_f32_16x16x32_f16(aA[mi], bA[nj], acc[mi][nj], 0, 0, 0);
          if (full) {
            acc[mi][nj] = __builtin_amdgcn_mfma_f32_16x16x32_f16(aA[mi], bB[nj], acc[mi][nj], 0, 0, 0);
            acc[mi][nj] = __builtin_amdgcn_mfma_f32_16x16x32_f16(aB[mi], bA[nj], acc[mi][nj], 0, 0, 0);
          }
        }
    }
  }

  const float* bsel = (wsel == 0) ? bq : (wsel == 1) ? bk : bv;
  _Float16* P1 = (wsel == 0) ? Q1 : K1;
  _Float16* P2 = (wsel == 0) ? Q2 : K2;
#pragma unroll
  for (int mi = 0; mi < 4; ++mi)
#pragma unroll
    for (int nj = 0; nj < 4; ++nj) {
      const int col = n0 + wn + nj * 16 + r16;
#pragma unroll
      for (int j = 0; j < 4; ++j) {
        const int rr = m0 + wm + mi * 16 + kg * 4 + j;
        if (wsel == 2) {
          V16[(size_t)rr * DD + col] = (_Float16)(acc[mi][nj][j] * INV65536 + bsel[col]);
        } else {
          // store 64*Q = acc/1024 + 64*bias
          const float qv = acc[mi][nj][j] * (1.0f / 1024.0f) + 64.0f * bsel[col];
          _Float16 h1, h2;
          split2(qv, h1, h2);
          P1[(size_t)rr * DD + col] = h1;
          P2[(size_t)rr * DD + col] = h2;
        }
      }
    }
}

// =====================================================================
// gemm_split<EPI>: A single-split fp16, B pre-split fp16x2 (NT).
// EPI 1: C = acc/65536 + bias + resid16    (w2 -> out), 2 products
// EPI 2: scores -> u16 keys, 1 product (Q1.K1), 32KB LDS,
//        grid 1D 2048 XCD-swizzled (batch -> one XCD).
// =====================================================================
template <int EPI>
__global__ __launch_bounds__(256) void gemm_split(const _Float16* __restrict__ A1,
                                                  const _Float16* __restrict__ B1g,
                                                  const _Float16* __restrict__ B2g,
                                                  const float* __restrict__ bias,
                                                  const _Float16* __restrict__ resid16,
                                                  float* __restrict__ C) {
  __shared__ _Float16 sm[(EPI == 2 ? 2 : 3) * 8192];
  _Float16* sA1 = sm;
  _Float16* sB1 = sm + 8192;
  _Float16* sB2 = sm + 16384;  // unused for EPI==2

  const int tid = threadIdx.x;
  const int lane = tid & 63, w = tid >> 6;
  const int r16 = lane & 15, kg = lane >> 4;
  const int rsub = lane >> 3, csub = lane & 7;
  const int wm = (w >> 1) * 64, wn = (w & 1) * 64;

  int n0, m0;
  if (EPI == 2) {
    // XCD swizzle: batch Bb's 64 blocks share id%8 = one XCD
    const int id = blockIdx.x;
    const int c8 = id & 7, t = id >> 3;   // t in 0..255
    const int Bb = ((t >> 6) << 3) + c8;  // batch 0..31
    const int r = (t >> 3) & 7;           // m sub-tile
    const int bx = t & 7;                 // n tile
    n0 = bx * 128;
    m0 = (Bb * 8 + r) * 128;
  } else {
    n0 = blockIdx.x * 128;
    m0 = blockIdx.y * 128;
  }

  const _Float16* pB1 = B1g;
  const _Float16* pB2 = B2g;
  if (EPI == 2) {
    const size_t boff = (size_t)(m0 >> 10) * NNODES * DD;
    pB1 += boff;
  }

  f32x4 acc[4][4];
#pragma unroll
  for (int i = 0; i < 4; ++i)
#pragma unroll
    for (int j = 0; j < 4; ++j) acc[i][j] = f32x4{0.f, 0.f, 0.f, 0.f};

  for (int k0 = 0; k0 < DD; k0 += 64) {
    __syncthreads();
#pragma unroll
    for (int it = 0; it < 4; ++it) {
      const int r = (w << 5) + (it << 3) + rsub;
      const int swz = ((csub ^ (r & 7)) << 3);
      const int ldso = (w << 11) + (it << 9);
      gll16(A1 + (size_t)(m0 + r) * DD + k0 + swz, sA1 + ldso);
      gll16(pB1 + (size_t)(n0 + r) * DD + k0 + swz, sB1 + ldso);
      if (EPI != 2) gll16(pB2 + (size_t)(n0 + r) * DD + k0 + swz, sB2 + ldso);
    }
    __syncthreads();

#pragma unroll
    for (int s = 0; s < 2; ++s) {
      half8 aA[4], bA[4], bB[4];
#pragma unroll
      for (int mi = 0; mi < 4; ++mi) {
        const int off = SWZ_OFF(wm + mi * 16 + r16, s * 4 + kg);
        aA[mi] = *(const half8*)(sA1 + off);
      }
#pragma unroll
      for (int nj = 0; nj < 4; ++nj) {
        const int off = SWZ_OFF(wn + nj * 16 + r16, s * 4 + kg);
        bA[nj] = *(const half8*)(sB1 + off);
        if (EPI != 2) bB[nj] = *(const half8*)(sB2 + off);
      }
#pragma unroll
      for (int mi = 0; mi < 4; ++mi)
#pragma unroll
        for (int nj = 0; nj < 4; ++nj) {
          acc[mi][nj] = __builtin_amdgcn_mfma_f32_16x16x32_f16(aA[mi], bA[nj], acc[mi][nj], 0, 0, 0);
          if (EPI != 2)
            acc[mi][nj] = __builtin_amdgcn_mfma_f32_16x16x32_f16(aA[mi], bB[nj], acc[mi][nj], 0, 0, 0);
        }
    }
  }

#pragma unroll
  for (int mi = 0; mi < 4; ++mi)
#pragma unroll
    for (int nj = 0; nj < 4; ++nj) {
      const int col = n0 + wn + nj * 16 + r16;
#pragma unroll
      for (int j = 0; j < 4; ++j) {
        const int rr = m0 + wm + mi * 16 + kg * 4 + j;
        const float v = acc[mi][nj][j] * INV65536;
        if (EPI == 2) {
          const float sv = v + bias[(size_t)(rr & (NNODES - 1)) * NNODES + col];
          const float f = fminf(fmaxf((sv + 8.0f) * 4096.0f, 0.0f), 65535.0f);
          uint16_t* kbase = (uint16_t*)((char*)C + (size_t)rr * 4096 + 2048);
          kbase[col] = (uint16_t)(unsigned)f;
        } else {
          C[(size_t)rr * DD + col] = v + bias[col] + (float)resid16[(size_t)rr * DD + col];
        }
      }
    }
}

// =====================================================================
// gemm_w1_ln: fused H = M@W1 + b1 -> LayerNorm -> ReLU -> H1 fp16(64*y).
// 64-row x 256-col blocks, 4 waves; each wave owns 16 FULL rows so LN
// is wave-local (16-lane shfl_xor row reductions, no LDS/barriers).
// A=M1 single split, B=W1 splits (2 products). acc = 16 x f32x4.
// Aliasing M1->H1 (same region) safe: block reads all K-slices of its
// own 64 rows (drained by the last barrier) before epilogue writes them.
// =====================================================================
__global__ __launch_bounds__(256) void gemm_w1_ln(const _Float16* __restrict__ M1,
                                                  const _Float16* __restrict__ B1g,
                                                  const _Float16* __restrict__ B2g,
                                                  const float* __restrict__ b1,
                                                  const float* __restrict__ lng,
                                                  const float* __restrict__ lnb,
                                                  _Float16* __restrict__ H1) {
  __shared__ _Float16 sm[4096 + 2 * 16384];  // A 8KB + B1 32KB + B2 32KB = 72KB
  _Float16* sA = sm;
  _Float16* sB1 = sm + 4096;
  _Float16* sB2 = sm + 4096 + 16384;

  const int tid = threadIdx.x;
  const int lane = tid & 63, w = tid >> 6;
  const int r16 = lane & 15, kg = lane >> 4;
  const int rsub = lane >> 3, csub = lane & 7;
  const int m0 = blockIdx.x * 64;

  f32x4 acc[16];
#pragma unroll
  for (int nf = 0; nf < 16; ++nf) acc[nf] = f32x4{0.f, 0.f, 0.f, 0.f};

  for (int k0 = 0; k0 < DD; k0 += 64) {
    __syncthreads();
    // A: 64 rows, 2 iters (wave w stages rows w*16+it*8+rsub)
#pragma unroll
    for (int it = 0; it < 2; ++it) {
      const int r = (w << 4) + (it << 3) + rsub;
      gll16(M1 + (size_t)(m0 + r) * DD + k0 + ((csub ^ (r & 7)) << 3),
            sA + (w << 10) + (it << 9));
    }
    // B: 256 n-rows per split, 8 iters (rows it*32 + w*8 + rsub)
#pragma unroll
    for (int it = 0; it < 8; ++it) {
      const int r = (it << 5) + (w << 3) + rsub;
      const size_t soff = (size_t)r * DD + k0 + ((csub ^ (r & 7)) << 3);
      const int ldso = (it << 11) + (w << 9);
      gll16(B1g + soff, sB1 + ldso);
      gll16(B2g + soff, sB2 + ldso);
    }
    __syncthreads();

#pragma unroll
    for (int s = 0; s < 2; ++s) {
      const half8 aA = *(const half8*)(sA + SWZ_OFF((w << 4) + r16, s * 4 + kg));
#pragma unroll
      for (int nf = 0; nf < 16; ++nf) {
        const int off = SWZ_OFF(nf * 16 + r16, s * 4 + kg);
        const half8 bA = *(const half8*)(sB1 + off);
        const half8 bB = *(const half8*)(sB2 + off);
        acc[nf] = __builtin_amdgcn_mfma_f32_16x16x32_f16(aA, bA, acc[nf], 0, 0, 0);
        acc[nf] = __builtin_amdgcn_mfma_f32_16x16x32_f16(aA, bB, acc[nf], 0, 0, 0);
      }
    }
  }

  // epilogue: per-row LN + ReLU, rows wave-local.
  float b1v[16], gv[16], bv[16];
#pragma unroll
  for (int nf = 0; nf < 16; ++nf) {
    const int c = nf * 16 + r16;
    b1v[nf] = b1[c];
    gv[nf] = lng[c];
    bv[nf] = lnb[c];
  }
#pragma unroll
  for (int j = 0; j < 4; ++j) {
    float h[16];
    float s = 0.0f;
#pragma unroll
    for (int nf = 0; nf < 16; ++nf) {
      h[nf] = acc[nf][j] * INV65536 + b1v[nf];
      s += h[nf];
    }
#pragma unroll
    for (int off = 1; off < 16; off <<= 1) s += __shfl_xor(s, off);
    const float mu = s * (1.0f / 256.0f);
    float sq = 0.0f;
#pragma unroll
    for (int nf = 0; nf < 16; ++nf) {
      const float d = h[nf] - mu;
      sq += d * d;
    }
#pragma unroll
    for (int off = 1; off < 16; off <<= 1) sq += __shfl_xor(sq, off);
    const float rstd = 1.0f / sqrtf(sq * (1.0f / 256.0f) + 1e-5f);
    const int row = m0 + (w << 4) + kg * 4 + j;
#pragma unroll
    for (int nf = 0; nf < 16; ++nf) {
      const float y = fmaxf((h[nf] - mu) * rstd * gv[nf] + bv[nf], 0.0f);
      H1[(size_t)row * DD + nf * 16 + r16] = (_Float16)(y * 64.0f);
    }
  }
}

// =====================================================================
// Top-64 from u16 keys + masked softmax + sparse messages. One wave/row.
// r10-proven structure (VGPR 32, occ 62%). Band +5/-4: 4-cell margin
// = 7 sigma of the 1-product score error (sigma ~0.57 cells) -- expected
// flips ~4e-5 over 33.5M scores. Candidates: exact fp32 recompute from
// split Q,K; jax tie semantics (score desc, index asc).
// =====================================================================
__global__ __launch_bounds__(256, 4) void topk_softmax_msg(float* __restrict__ S,
                                                           const _Float16* __restrict__ V16,
                                                           const _Float16* __restrict__ Q1,
                                                           const _Float16* __restrict__ Q2,
                                                           const _Float16* __restrict__ K1,
                                                           const _Float16* __restrict__ K2,
                                                           const float* __restrict__ adj,
                                                           _Float16* __restrict__ M1) {
  const int tid = threadIdx.x;
  const int w = tid >> 6, lane = tid & 63;
  // XCD swizzle: batch = (t>>8)*8 + id%8 -> whole batch on one XCD
  const int id = blockIdx.x;            // 0..8191
  const int xcd = id & 7, t = id >> 3;  // t 0..1023
  const int b = (t >> 8) * 8 + xcd;     // batch 0..31
  const int row = b * NNODES + (t & 255) * 4 + w;
  const int m = row & (NNODES - 1);
  float* Srow = S + (size_t)row * NNODES;
  const uint16_t* krow = (const uint16_t*)((const char*)S + (size_t)row * 4096 + 2048);

  __shared__ float2 spair[4][KNB];  // (wgt, V16 row byte-offset bits)
  __shared__ int cidxs[4][32];
  __shared__ float cex[4][32];
  __shared__ int csel[4][32];

  if (lane < KNB) spair[w][lane] = make_float2(0.0f, __int_as_float(0));

  // load 16 keys: cols g*512 + lane*8 + e
  const uint4 u0 = *(const uint4*)(krow + lane * 8);
  const uint4 u1 = *(const uint4*)(krow + 512 + lane * 8);
  int k[16];
  {
    const unsigned uu[8] = {u0.x, u0.y, u0.z, u0.w, u1.x, u1.y, u1.z, u1.w};
#pragma unroll
    for (int q = 0; q < 8; ++q) {
      k[q * 2] = (int)(uu[q] & 0xffffu);
      k[q * 2 + 1] = (int)(uu[q] >> 16);
    }
  }
  // k[t] maps to col(t) = (t>>3)*512 + lane*8 + (t&7)

  float st[16];
#pragma unroll
  for (int t2 = 0; t2 < 16; ++t2) st[t2] = fmaf((float)k[t2] + 0.5f, KCELL, -8.0f);

  // radix-select 64th-largest key (16 bits)
  int cur = 0;
#pragma unroll 1
  for (int bit = 15; bit >= 0; --bit) {
    const int cand = cur | (1 << bit);
    int cnt = 0;
#pragma unroll
    for (int t2 = 0; t2 < 16; ++t2) cnt += (int)__popcll(__ballot(k[t2] >= cand));
    if (cnt >= KNB) cur = cand;
  }

  const int kHi = cur + 5;  // key >= kHi -> provably in top-64
  const int kLo = cur - 4;  // key <  kLo -> provably out

  const unsigned long long ltmask = (1ull << lane) - 1ull;
  unsigned hm = 0u, cm = 0u;
  int cpos[16];
  int nhi = 0, ncand = 0;
#pragma unroll
  for (int g = 0; g < 2; ++g) {
    bool hiv[8], cdv[8];
    unsigned long long mh[8], mc[8];
#pragma unroll
    for (int e = 0; e < 8; ++e) {
      const int t2 = g * 8 + e;
      hiv[e] = (k[t2] >= kHi);
      cdv[e] = (!hiv[e]) && (k[t2] >= kLo);
      mh[e] = __ballot(hiv[e]);
      mc[e] = __ballot(cdv[e]);
    }
    int below = 0, tot_h = 0, tot_c = 0;
#pragma unroll
    for (int e = 0; e < 8; ++e) {
      below += (int)__popcll(mc[e] & ltmask);
      tot_h += (int)__popcll(mh[e]);
      tot_c += (int)__popcll(mc[e]);
    }
    int own = 0;
#pragma unroll
    for (int e = 0; e < 8; ++e) {
      const int t2 = g * 8 + e;
      cpos[t2] = -1;
      if (hiv[e]) hm |= (1u << t2);
      if (cdv[e]) {
        cm |= (1u << t2);
        const int p = ncand + below + own;
        cpos[t2] = p;
        if (p < 32) cidxs[w][p] = g * 512 + lane * 8 + e;
        ++own;
      }
    }
    nhi += tot_h;
    ncand += tot_c;
  }
  const int need = KNB - nhi;  // >= 1; nhi+ncand >= 64

  unsigned selm;
  if (ncand == need) {
    selm = hm | cm;  // fast path (most rows)
  } else {
    const int nc = (ncand <= 32) ? ncand : 32;
    const int nd = (need <= nc) ? need : nc;
    const size_t qoff = (size_t)row * DD + lane * 4;
    const half4 q1v = *(const half4*)(Q1 + qoff);
    const half4 q2v = *(const half4*)(Q2 + qoff);
    float qf[4];
#pragma unroll
    for (int e = 0; e < 4; ++e) qf[e] = (float)q1v[e] + (float)q2v[e];
    const float* adjrow = adj + (size_t)m * NNODES;
#pragma unroll 2
    for (int t2 = 0; t2 < nc; ++t2) {
      const int j = cidxs[w][t2];
      const size_t koff = ((size_t)b * NNODES + j) * DD + lane * 4;
      const half4 k1v = *(const half4*)(K1 + koff);
      const half4 k2v = *(const half4*)(K2 + koff);
      float part = 0.0f;
#pragma unroll
      for (int e = 0; e < 4; ++e) part = fmaf(qf[e], (float)k1v[e] + (float)k2v[e], part);
#pragma unroll
      for (int off = 32; off > 0; off >>= 1) part += __shfl_xor(part, off);
      if (lane == 0) cex[w][t2] = part * INV65536 + adjrow[j];
    }
    if (lane < nc) {
      const float et = cex[w][lane];
      int rank = 0;
      for (int u = 0; u < nc; ++u) {
        const float eu = cex[w][u];
        rank += (eu > et || (eu == et && u < lane)) ? 1 : 0;
      }
      csel[w][lane] = (rank < nd) ? 1 : 0;
    }
    selm = hm;
#pragma unroll
    for (int t2 = 0; t2 < 16; ++t2) {
      if (((cm >> t2) & 1u) && cpos[t2] >= 0 && cpos[t2] < 32 && csel[w][cpos[t2]]) selm |= (1u << t2);
    }
  }

  // softmax over selected (rmax over all; the max element is hi|cand)
  float rmax = st[0];
#pragma unroll
  for (int t2 = 1; t2 < 16; ++t2) rmax = fmaxf(rmax, st[t2]);
#pragma unroll
  for (int off = 32; off > 0; off >>= 1) rmax = fmaxf(rmax, __shfl_xor(rmax, off));

  float p[16];
  float sum = 0.0f;
#pragma unroll
  for (int t2 = 0; t2 < 16; ++t2) {
    p[t2] = __expf(st[t2] - rmax);
    if ((selm >> t2) & 1u) sum += p[t2];
  }
#pragma unroll
  for (int off = 32; off > 0; off >>= 1) sum += __shfl_xor(sum, off);
  const float inv = 1.0f / sum;

  // attn write (overwrites full 4KB row incl. key half) + ordered compaction
  int run = 0;
#pragma unroll
  for (int g = 0; g < 2; ++g) {
    bool sel8[8];
    unsigned long long ms[8];
#pragma unroll
    for (int e = 0; e < 8; ++e) {
      sel8[e] = (selm >> (g * 8 + e)) & 1u;
      ms[e] = __ballot(sel8[e]);
    }
    int below = 0, tot = 0;
#pragma unroll
    for (int e = 0; e < 8; ++e) {
      below += (int)__popcll(ms[e] & ltmask);
      tot += (int)__popcll(ms[e]);
    }
    float ow[8];
    int own = 0;
#pragma unroll
    for (int e = 0; e < 8; ++e) {
      const int t2 = g * 8 + e;
      const float aw = sel8[e] ? p[t2] * inv : 0.0f;
      ow[e] = aw;
      if (sel8[e]) {
        const int pos = run + below + own;
        // store V16 row byte-offset: col * DD * 2
        if (pos < KNB)
          spair[w][pos] = make_float2(aw, __int_as_float((g * 512 + lane * 8 + e) * (DD * 2)));
        ++own;
      }
    }
    float* dst = Srow + g * 512 + lane * 8;
    *(float4*)(dst) = make_float4(ow[0], ow[1], ow[2], ow[3]);
    *(float4*)(dst + 4) = make_float4(ow[4], ow[5], ow[6], ow[7]);
    run += tot;
  }

  // messages: lane owns output dims [lane*4, lane*4+4)
  float4 acc = {0.0f, 0.0f, 0.0f, 0.0f};
  const char* Vbase = (const char*)(V16 + (size_t)b * NNODES * DD) + lane * 8;
#pragma unroll 4
  for (int t2 = 0; t2 < KNB; ++t2) {
    const float2 pr = spair[w][t2];
    const int off = __float_as_int(pr.y);
    const half4 vv = *(const half4*)(Vbase + off);
    acc.x = fmaf(pr.x, (float)vv[0], acc.x);
    acc.y = fmaf(pr.x, (float)vv[1], acc.y);
    acc.z = fmaf(pr.x, (float)vv[2], acc.z);
    acc.w = fmaf(pr.x, (float)vv[3], acc.w);
  }
  // M stored as single fp16(64*m) -- downstream w1 runs 2-product
  half4 m1;
  m1[0] = (_Float16)(acc.x * 64.0f);
  m1[1] = (_Float16)(acc.y * 64.0f);
  m1[2] = (_Float16)(acc.z * 64.0f);
  m1[3] = (_Float16)(acc.w * 64.0f);
  *(half4*)(M1 + (size_t)row * DD + lane * 4) = m1;
}

// =====================================================================
// Host launch
// =====================================================================
extern "C" void kernel_launch(void* const* d_in, const int* in_sizes, int n_in,
                              void* d_out, int out_size, void* d_ws, size_t ws_size,
                              hipStream_t stream) {
  (void)in_sizes; (void)n_in; (void)out_size; (void)ws_size;
  const float* x   = (const float*)d_in[0];
  const float* wq  = (const float*)d_in[1];
  const float* bq  = (const float*)d_in[2];
  const float* wk  = (const float*)d_in[3];
  const float* bk  = (const float*)d_in[4];
  const float* wv  = (const float*)d_in[5];
  const float* bv  = (const float*)d_in[6];
  const float* adj = (const float*)d_in[7];
  const float* w1  = (const float*)d_in[8];
  const float* b1  = (const float*)d_in[9];
  const float* lng = (const float*)d_in[10];
  const float* lnb = (const float*)d_in[11];
  const float* w2  = (const float*)d_in[12];
  const float* b2  = (const float*)d_in[13];

  const size_t BND = (size_t)MTOT * DD;  // 8,388,608
  float* outp  = (float*)d_out;          // [MTOT][256] (written by final w2 gemm)
  float* attnp = outp + BND;             // [MTOT][1024] (X splits -> keys+attn)

  // X1/X2 live in the attn scratch region (dead before scores writes keys)
  _Float16* X1 = (_Float16*)attnp;
  _Float16* X2 = X1 + BND;

  _Float16* Q1 = (_Float16*)d_ws;   // ~85 MB total ws use (proven available)
  _Float16* Q2 = Q1 + BND;
  _Float16* K1 = Q2 + BND;
  _Float16* K2 = K1 + BND;
  _Float16* WT = K2 + BND;          // [5][2][65536]
  _Float16* V16 = WT + 5 * 131072;  // fp16 V (16.78 MB)

  _Float16* M1 = Q1;   // reuse after topk (wave reads own Q row first)
  _Float16* H1 = Q1;   // fused w1+ln writes in place (block-local rows)

  const dim3 blk(256);

  prep_wx<<<dim3(5376), blk, 0, stream>>>(x, X1, X2, wq, wk, wv, w1, w2, WT);
  gemm_qkv<<<dim3(1536), blk, 0, stream>>>(X1, X2, WT, bq, bk, bv, Q1, Q2, K1, K2, V16);
  gemm_split<2><<<dim3(2048), blk, 0, stream>>>(Q1, K1, K2, adj, nullptr, attnp);
  topk_softmax_msg<<<dim3(MTOT / 4), blk, 0, stream>>>(attnp, V16, Q1, Q2, K1, K2, adj, M1);
  gemm_w1_ln<<<dim3(MTOT / 64), blk, 0, stream>>>(M1, WT + 3 * 131072, WT + 3 * 131072 + 65536,
                                                  b1, lng, lnb, H1);
  gemm_split<1><<<dim3(2, 256), blk, 0, stream>>>(H1, WT + 4 * 131072, WT + 4 * 131072 + 65536,
                                                  b2, V16, outp);
}